// Round 3
// baseline (721.779 us; speedup 1.0000x reference)
//
#include <hip/hip_runtime.h>
#include <stdint.h>

#define N_NODES 32768
#define N_EDGES 262144
#define NB 8
#define TW 25

typedef __attribute__((ext_vector_type(8))) short short8;
typedef __attribute__((ext_vector_type(4))) float floatx4;

#if defined(__has_builtin)
#if __has_builtin(__builtin_amdgcn_cvt_pk_bf16_f32)
#define HAVE_CVT_PK_BF16 1
#endif
#endif

// swish via HW approximate reciprocal (v_rcp_f32): ~1-ulp rel error,
// far below bf16 quantization; avoids the ~10-instr IEEE divide sequence.
__device__ __forceinline__ float swishf(float x) {
    return x * __builtin_amdgcn_rcpf(1.0f + __expf(-x));
}

__device__ __forceinline__ unsigned short f2bf(float x) {
    union { float f; unsigned u; } v; v.f = x;
    unsigned r = v.u + 0x7FFFu + ((v.u >> 16) & 1u);
    return (unsigned short)(r >> 16);
}
// packed f32x2 -> bf16x2 (low = a, high = b); HW v_cvt_pk_bf16_f32 on gfx950
__device__ __forceinline__ unsigned pkbf(float a, float b) {
#ifdef HAVE_CVT_PK_BF16
    typedef __attribute__((ext_vector_type(2))) __bf16 bf16x2;
    union { bf16x2 v; unsigned u; } cv;
    cv.v = __builtin_amdgcn_cvt_pk_bf16_f32(a, b);
    return cv.u;
#else
    return (unsigned)f2bf(a) | ((unsigned)f2bf(b) << 16);
#endif
}
__device__ __forceinline__ float bf2f(unsigned short b) {
    union { unsigned u; float f; } v; v.u = ((unsigned)b) << 16; return v.f;
}

// ---------------------------------------------------------------------------
// init: posx/post + per-node static feature tail feat[32] = [u(25), posx, post, 0x5] bf16
__global__ void init_kernel(const float* __restrict__ pos, const float* __restrict__ u,
                            float* __restrict__ posx, float* __restrict__ post,
                            unsigned short* __restrict__ feat) {
    int i = blockIdx.x * 256 + threadIdx.x;
    if (i < N_NODES) {
        float pt = pos[i * 2 + 0] * 0.25f;
        float px = pos[i * 2 + 1] * 0.0625f;
        post[i] = pt;
        posx[i] = px;
        unsigned short f[32];
        #pragma unroll
        for (int k = 0; k < 25; ++k) f[k] = f2bf(u[(size_t)i * 25 + k]);
        f[25] = f2bf(px);
        f[26] = f2bf(pt);
        #pragma unroll
        for (int k = 27; k < 32; ++k) f[k] = 0;
        #pragma unroll
        for (int j = 0; j < 4; ++j)
            *(uint4*)(feat + (size_t)i * 32 + j * 8) = *(uint4*)&f[j * 8];
    }
}

__global__ void deg_kernel(const int* __restrict__ tgt, int* __restrict__ deg) {
    int i = blockIdx.x * 256 + threadIdx.x;
    if (i < N_EDGES) atomicAdd(&deg[tgt[i]], 1);
}

// exclusive scan of deg -> cursor, single block
__global__ __launch_bounds__(1024) void scan_kernel(const int* __restrict__ deg,
                                                    int* __restrict__ cursor) {
    __shared__ int ps[1024];
    int t = threadIdx.x;
    int base = t * 32;
    int tot = 0;
    for (int i = 0; i < 32; ++i) tot += deg[base + i];
    ps[t] = tot;
    __syncthreads();
    for (int off = 1; off < 1024; off <<= 1) {
        int v = (t >= off) ? ps[t - off] : 0;
        __syncthreads();
        ps[t] += v;
        __syncthreads();
    }
    int run = ps[t] - tot;
    for (int i = 0; i < 32; ++i) {
        cursor[base + i] = run;
        run += deg[base + i];
    }
}

// tgt-sorted edge arrays directly
__global__ void scatter_kernel(const int* __restrict__ src, const int* __restrict__ tgt,
                               int* __restrict__ cursor,
                               int* __restrict__ src_s, int* __restrict__ tgt_s) {
    int i = blockIdx.x * 256 + threadIdx.x;
    if (i < N_EDGES) {
        int tg = tgt[i];
        int p = atomicAdd(&cursor[tg], 1);
        src_s[p] = src[i];
        tgt_s[p] = tg;
    }
}

// ---------------------------------------------------------------------------
// Pack weight into MFMA B-frag order: frag id = ((l*Kc + c)*8 + t8)*64 + lane,
// lane holds B[k=c*32+(lane>>4)*8+j][n=t8*16+(lane&15)], j=0..7.
__global__ __launch_bounds__(256) void pack_kernel(const float* __restrict__ W,
                                                   unsigned short* __restrict__ Wp,
                                                   int Kreal, int Kc, int total) {
    int id = blockIdx.x * 256 + threadIdx.x;
    if (id >= total) return;
    int lane = id & 63;
    int t8 = (id >> 6) & 7;
    int rest = id >> 9;
    int c = rest % Kc;
    int l = rest / Kc;
    int n = t8 * 16 + (lane & 15);
    int kb = c * 32 + (lane >> 4) * 8;
    short8 v;
    #pragma unroll
    for (int j = 0; j < 8; ++j) {
        int k = kb + j;
        float x = (k < Kreal) ? W[((size_t)l * Kreal + k) * 128 + n] : 0.f;
        v[j] = (short)f2bf(x);
    }
    *(short8*)(Wp + (size_t)id * 8) = v;
}

// Pack the message GEMM1 weight (283x128 per layer) into the per-node
// projection form Wcat (160 x 256): cols 0..127 -> A_t, 128..255 -> A_s.
//   k<128   : h rows      (A_t: rows 0..127;  A_s: rows 128..255)
//   k=128..152: u_diff rows 256..280   (A_s negated)
//   k=153   : p_diff row 281           (A_s negated)
//   k=154   : var_i row 282            (A_s zero)
// frag id = ((l*5 + c)*16 + tile)*64 + lane; 6*5*16*64 = 30720 ids total.
__global__ __launch_bounds__(256) void pack_cat_kernel(const float* __restrict__ Wm1,
                                                       unsigned short* __restrict__ Wp) {
    int id = blockIdx.x * 256 + threadIdx.x;
    if (id >= 30720) return;
    int lane = id & 63;
    int tile = (id >> 6) & 15;
    int rest = id >> 10;
    int c = rest % 5;
    int l = rest / 5;
    int n = tile * 16 + (lane & 15);
    int col = n & 127;
    bool isT = n < 128;
    int kb = c * 32 + (lane >> 4) * 8;
    const float* W = Wm1 + (size_t)l * 283 * 128;
    short8 v;
    #pragma unroll
    for (int j = 0; j < 8; ++j) {
        int k = kb + j;
        float x = 0.f;
        if (k < 128) {
            x = W[(size_t)(isT ? k : 128 + k) * 128 + col];
        } else if (k < 155) {
            int row = 256 + (k - 128);   // 256..282
            x = W[(size_t)row * 128 + col];
            if (!isT) x = (row == 282) ? 0.f : -x;
        }
        v[j] = (short)f2bf(x);
    }
    *(short8*)(Wp + (size_t)id * 8) = v;
}

// ---------------------------------------------------------------------------
// Encoder; writes hraw (bf16, unnormalized h) and zeroes this block's agg slice
__global__ __launch_bounds__(256) void encoder_kernel(
    const float* __restrict__ u, const float* __restrict__ posx,
    const float* __restrict__ post,
    const float* __restrict__ We1, const float* __restrict__ be1,
    const float* __restrict__ We2, const float* __restrict__ be2,
    unsigned short* __restrict__ hraw, float* __restrict__ agg)
{
    __shared__ __align__(16) float As_[64 * 36];
    __shared__ __align__(16) float Ws[32 * 128];
    __shared__ __align__(16) float Ms[64 * 128];

    int t = threadIdx.x;
    int n0 = blockIdx.x * 64;
    int rg = t >> 5, cg = t & 31;

    {   // zero agg slice
        int r = t & 63, cseg = t >> 6;
        float4 z = make_float4(0.f, 0.f, 0.f, 0.f);
        #pragma unroll
        for (int j = 0; j < 8; ++j)
            *(float4*)(agg + (size_t)(n0 + r) * 128 + cseg * 32 + j * 4) = z;
    }

    float acc[8][4] = {};
    {
        int kk = t >> 3, cb = (t & 7) * 16;
        #pragma unroll
        for (int j = 0; j < 4; ++j) {
            float4 w = make_float4(0.f, 0.f, 0.f, 0.f);
            if (kk < 27) w = *(const float4*)&We1[kk * 128 + cb + j * 4];
            *(float4*)&Ws[kk * 128 + cb + j * 4] = w;
        }
        int el = t >> 2, kb = (t & 3) * 8, n = n0 + el;
        float v[8];
        #pragma unroll
        for (int j = 0; j < 8; ++j) {
            int k = kb + j;
            float x = 0.f;
            if (k < 25) x = u[n * 25 + k];
            else if (k == 25) x = posx[n];
            else if (k == 26) x = post[n];
            v[j] = x;
        }
        #pragma unroll
        for (int j = 0; j < 8; j += 4)
            *(float4*)&As_[el * 36 + kb + j] = make_float4(v[j], v[j+1], v[j+2], v[j+3]);
        __syncthreads();
        #pragma unroll 4
        for (int kk2 = 0; kk2 < 32; ++kk2) {
            float4 b = *(const float4*)&Ws[kk2 * 128 + cg * 4];
            float a[8];
            #pragma unroll
            for (int i = 0; i < 8; ++i) a[i] = As_[(rg * 8 + i) * 36 + kk2];
            #pragma unroll
            for (int i = 0; i < 8; ++i) {
                acc[i][0] += a[i] * b.x; acc[i][1] += a[i] * b.y;
                acc[i][2] += a[i] * b.z; acc[i][3] += a[i] * b.w;
            }
        }
        __syncthreads();
    }
    {
        float4 b1 = *(const float4*)&be1[cg * 4];
        #pragma unroll
        for (int i = 0; i < 8; ++i) {
            float4 m;
            m.x = swishf(acc[i][0] + b1.x);
            m.y = swishf(acc[i][1] + b1.y);
            m.z = swishf(acc[i][2] + b1.z);
            m.w = swishf(acc[i][3] + b1.w);
            *(float4*)&Ms[(rg * 8 + i) * 128 + cg * 4] = m;
        }
        __syncthreads();
    }
    float acc2[8][4] = {};
    for (int k0 = 0; k0 < 128; k0 += 32) {
        int kk = t >> 3, cb = (t & 7) * 16;
        #pragma unroll
        for (int j = 0; j < 4; ++j)
            *(float4*)&Ws[kk * 128 + cb + j * 4] =
                *(const float4*)&We2[(k0 + kk) * 128 + cb + j * 4];
        __syncthreads();
        #pragma unroll 4
        for (int kk2 = 0; kk2 < 32; ++kk2) {
            float4 b = *(const float4*)&Ws[kk2 * 128 + cg * 4];
            float a[8];
            #pragma unroll
            for (int i = 0; i < 8; ++i) a[i] = Ms[(rg * 8 + i) * 128 + (k0 + kk2)];
            #pragma unroll
            for (int i = 0; i < 8; ++i) {
                acc2[i][0] += a[i] * b.x; acc2[i][1] += a[i] * b.y;
                acc2[i][2] += a[i] * b.z; acc2[i][3] += a[i] * b.w;
            }
        }
        __syncthreads();
    }
    {
        float4 b2 = *(const float4*)&be2[cg * 4];
        #pragma unroll
        for (int i = 0; i < 8; ++i) {
            int n = n0 + rg * 8 + i;
            float4 o;
            o.x = swishf(acc2[i][0] + b2.x);
            o.y = swishf(acc2[i][1] + b2.y);
            o.z = swishf(acc2[i][2] + b2.z);
            o.w = swishf(acc2[i][3] + b2.w);
            uint2 pk;
            pk.x = pkbf(o.x, o.y);
            pk.y = pkbf(o.z, o.w);
            *(uint2*)(hraw + (size_t)n * 128 + cg * 4) = pk;
        }
    }
}

// ---------------------------------------------------------------------------
// Per-node pre-message projection (replaces per-edge GEMM1):
//   h_norm = (hraw - mean)/std  (skip when donorm==0),   written to h_bf
//   [A_t | A_s] = [h_norm(128) | feat(32)] @ Wcat(160x256)   (+ b1 on A_t)
// 64 nodes/block, 512 threads (8 waves), wave w owns col tiles w (A_t) and 8+w (A_s).
__global__ __launch_bounds__(512, 4) void premsg_kernel(
    const unsigned short* __restrict__ hraw,
    const float* __restrict__ stats, int donorm,
    const unsigned short* __restrict__ feat,
    const unsigned short* __restrict__ Wp, const float* __restrict__ b1,
    unsigned short* __restrict__ h_bf,
    float* __restrict__ At, float* __restrict__ As)
{
    __shared__ __align__(16) unsigned short A[64 * 168];   // 21504 B
    __shared__ float mean_s[128];
    __shared__ float rstd_s[128];

    int t = threadIdx.x;
    int n0 = blockIdx.x * 64;
    int bidx = n0 >> 12;

    if (t < 128) {
        float mn = 0.f, rs = 1.f;
        if (donorm) {
            float s1 = stats[bidx * 128 + t] * (1.f / 4096.f);
            float s2 = stats[(NB + bidx) * 128 + t] * (1.f / 4096.f);
            mn = s1;
            rs = rsqrtf(s2 - s1 * s1 + 1e-5f);
        }
        mean_s[t] = mn;
        rstd_s[t] = rs;
    }
    __syncthreads();

    {   // stage [h_norm | feat] into LDS; also write h_bf
        int r = t & 63, cseg = t >> 6;
        int n = n0 + r;
        uint4 raw0 = *(const uint4*)(hraw + (size_t)n * 128 + cseg * 16);
        uint4 raw1 = *(const uint4*)(hraw + (size_t)n * 128 + cseg * 16 + 8);
        unsigned pk[8];
        #pragma unroll
        for (int j = 0; j < 8; ++j) {
            unsigned word = (j < 4) ? ((const unsigned*)&raw0)[j]
                                    : ((const unsigned*)&raw1)[j - 4];
            int c0 = cseg * 16 + j * 2;
            float v0 = (bf2f((unsigned short)(word & 0xffffu)) - mean_s[c0]) * rstd_s[c0];
            float v1 = (bf2f((unsigned short)(word >> 16)) - mean_s[c0 + 1]) * rstd_s[c0 + 1];
            pk[j] = pkbf(v0, v1);
        }
        *(uint4*)(A + r * 168 + cseg * 16)     = *(uint4*)&pk[0];
        *(uint4*)(A + r * 168 + cseg * 16 + 8) = *(uint4*)&pk[4];
        *(uint4*)(h_bf + (size_t)n * 128 + cseg * 16)     = *(uint4*)&pk[0];
        *(uint4*)(h_bf + (size_t)n * 128 + cseg * 16 + 8) = *(uint4*)&pk[4];
        if (cseg < 2) {
            uint4 f0 = *(const uint4*)(feat + (size_t)n * 32 + cseg * 16);
            uint4 f1 = *(const uint4*)(feat + (size_t)n * 32 + cseg * 16 + 8);
            *(uint4*)(A + r * 168 + 128 + cseg * 16)     = f0;
            *(uint4*)(A + r * 168 + 128 + cseg * 16 + 8) = f1;
        }
    }
    __syncthreads();

    int w = t >> 6, lane = t & 63, q = lane >> 4, m = lane & 15;
    floatx4 accT[4] = {};
    floatx4 accS[4] = {};
    #pragma unroll
    for (int c = 0; c < 5; ++c) {
        short8 bT = *(const short8*)(Wp + ((size_t)(c * 16 + w) * 64 + lane) * 8);
        short8 bS = *(const short8*)(Wp + ((size_t)(c * 16 + 8 + w) * 64 + lane) * 8);
        #pragma unroll
        for (int g2 = 0; g2 < 4; ++g2) {
            short8 a = *(const short8*)(A + (g2 * 16 + m) * 168 + c * 32 + q * 8);
            accT[g2] = __builtin_amdgcn_mfma_f32_16x16x32_bf16(a, bT, accT[g2], 0, 0, 0);
            accS[g2] = __builtin_amdgcn_mfma_f32_16x16x32_bf16(a, bS, accS[g2], 0, 0, 0);
        }
    }
    int col = w * 16 + m;
    float bv = b1[col];
    #pragma unroll
    for (int g2 = 0; g2 < 4; ++g2) {
        #pragma unroll
        for (int r = 0; r < 4; ++r) {
            int row = g2 * 16 + q * 4 + r;
            At[(size_t)(n0 + row) * 128 + col] = accT[g2][r] + bv;
            As[(size_t)(n0 + row) * 128 + col] = accS[g2][r];
        }
    }
}

// ---------------------------------------------------------------------------
// Message: register-A restructure. 64 tgt-sorted edges/block, 256 threads
// (4 waves); wave w owns edges w*16..w*16+16 x ALL 128 output cols.
// Each lane (q,m) computes its MFMA A-frag directly in registers:
//   A[row=m][k=c*32+q*8+j] = swish(At[tgt[m]][k] + As[src[m]][k])
// -> no LDS staging of A, no Msh round trip, 1 barrier (tgtS only).
// Epilogue/reduction use a per-wave-private Cs region (wave-synchronous LDS).
__global__ __launch_bounds__(256, 4) void message_kernel(
    const float* __restrict__ At, const float* __restrict__ As,
    const int* __restrict__ src_s, const int* __restrict__ tgt_s,
    const unsigned short* __restrict__ W2p, const float* __restrict__ b2,
    float* __restrict__ agg, float* __restrict__ stats)
{
    __shared__ __align__(16) unsigned short Cs[64 * 132];   // 16896 B
    __shared__ int tgtS[64];

    int t = threadIdx.x;
    int e0 = blockIdx.x * 64;
    if (blockIdx.x == 0) {  // zero stats for this layer (t*8 covers 2048 floats)
        float4 z = make_float4(0.f, 0.f, 0.f, 0.f);
        *(float4*)&stats[t * 8] = z;
        *(float4*)&stats[t * 8 + 4] = z;
    }
    if (t < 64) tgtS[t] = tgt_s[e0 + t];
    __syncthreads();

    int w = t >> 6, lane = t & 63, q = lane >> 4, m = lane & 15;
    int erow = w * 16 + m;           // this lane's edge (A-frag row)
    int e = e0 + erow;
    int gg = tgtS[erow];
    int ss = src_s[e];

    // ---- gather At/As k-slices for this lane's A-frags (issue all 16 loads)
    const float* atp = At + (size_t)gg * 128 + q * 8;
    const float* asp = As + (size_t)ss * 128 + q * 8;
    float4 va[8], vb[8];
    #pragma unroll
    for (int c = 0; c < 4; ++c) {
        va[2 * c]     = *(const float4*)(atp + c * 32);
        va[2 * c + 1] = *(const float4*)(atp + c * 32 + 4);
        vb[2 * c]     = *(const float4*)(asp + c * 32);
        vb[2 * c + 1] = *(const float4*)(asp + c * 32 + 4);
    }
    // ---- A-frags in registers: swish + pack
    short8 af[4];
    #pragma unroll
    for (int c = 0; c < 4; ++c) {
        float4 a0 = va[2 * c], b0 = vb[2 * c];
        float4 a1 = va[2 * c + 1], b1 = vb[2 * c + 1];
        union { unsigned u[4]; short8 s; } pk_;
        pk_.u[0] = pkbf(swishf(a0.x + b0.x), swishf(a0.y + b0.y));
        pk_.u[1] = pkbf(swishf(a0.z + b0.z), swishf(a0.w + b0.w));
        pk_.u[2] = pkbf(swishf(a1.x + b1.x), swishf(a1.y + b1.y));
        pk_.u[3] = pkbf(swishf(a1.z + b1.z), swishf(a1.w + b1.w));
        af[c] = pk_.s;
    }

    // ---- GEMM2: 4 K-chunks x 8 col-tiles, B-frags straight from global (L1/L2)
    floatx4 acc[8] = {};
    #pragma unroll
    for (int c = 0; c < 4; ++c) {
        #pragma unroll
        for (int t8 = 0; t8 < 8; ++t8) {
            short8 b = *(const short8*)(W2p + ((size_t)(c * 8 + t8) * 64 + lane) * 8);
            acc[t8] = __builtin_amdgcn_mfma_f32_16x16x32_bf16(af[c], b, acc[t8], 0, 0, 0);
        }
    }

    // ---- epilogue: swish + write per-wave Cs region (rows w*16..w*16+16)
    #pragma unroll
    for (int t8 = 0; t8 < 8; ++t8) {
        float bv = b2[t8 * 16 + m];
        unsigned p01 = pkbf(swishf(acc[t8][0] + bv), swishf(acc[t8][1] + bv));
        unsigned p23 = pkbf(swishf(acc[t8][2] + bv), swishf(acc[t8][3] + bv));
        int rb = (w * 16 + q * 4) * 132 + t8 * 16 + m;
        Cs[rb]           = (unsigned short)p01;
        Cs[rb + 132]     = (unsigned short)(p01 >> 16);
        Cs[rb + 2 * 132] = (unsigned short)p23;
        Cs[rb + 3 * 132] = (unsigned short)(p23 >> 16);
    }

    // ---- reduction over this wave's 16 rows (wave-synchronous: same wave wrote
    //      this Cs region; program order + lgkmcnt gives the ordering)
    {
        int r0 = w * 16;
        int col0 = lane;                 // cols lane and lane+64
        float run0 = 0.f, run1 = 0.f;
        int prev = tgtS[r0];
        bool atStart = true;
        #pragma unroll 4
        for (int i = 0; i < 16; ++i) {
            int tg = tgtS[r0 + i];
            if (tg != prev) {
                float* d0 = &agg[(size_t)prev * 128 + col0];
                if (atStart) { atomicAdd(d0, run0); atomicAdd(d0 + 64, run1); }
                else         { d0[0] = run0;        d0[64] = run1; }
                run0 = 0.f; run1 = 0.f; prev = tg; atStart = false;
            }
            run0 += bf2f(Cs[(r0 + i) * 132 + col0]);
            run1 += bf2f(Cs[(r0 + i) * 132 + col0 + 64]);
        }
        float* d0 = &agg[(size_t)prev * 128 + col0];
        atomicAdd(d0, run0);
        atomicAdd(d0 + 64, run1);
    }
}

// ---------------------------------------------------------------------------
// Update MLP: unchanged. Residual from staged A region; writes pre-norm hraw
// + fused batch stats; zeroes agg slice for next layer.
__global__ __launch_bounds__(512, 4) void update_kernel(
    unsigned short* __restrict__ hraw, const unsigned short* __restrict__ h_bf,
    float* __restrict__ agg, const int* __restrict__ deg,
    const float* __restrict__ post,
    const unsigned short* __restrict__ W1p, const float* __restrict__ b1,
    const unsigned short* __restrict__ W2p, const float* __restrict__ b2,
    float* __restrict__ stats)
{
    __shared__ __align__(16) unsigned short SH[64 * 296 + 64 * 136];  // 55296 B
    unsigned short* Msh = SH + 64 * 296;

    int t = threadIdx.x;
    int n0 = blockIdx.x * 64;

    // ---- stage A = [h_bf | agg/deg (bf16) | post-pad]: 8 threads/row
    {
        int r = t & 63, cseg = t >> 6;
        int n = n0 + r;
        const short8* hn = (const short8*)(h_bf + (size_t)n * 128);
        #pragma unroll
        for (int j = 0; j < 2; ++j) {
            int chunk = cseg * 2 + j;
            *(short8*)(SH + r * 296 + chunk * 8) = hn[chunk];
        }
        float ic = __builtin_amdgcn_rcpf(fmaxf((float)deg[n], 1.0f));
        #pragma unroll
        for (int j = 0; j < 2; ++j) {
            int unit = cseg * 2 + j;
            const float* ap = agg + (size_t)n * 128 + unit * 8;
            float4 v0 = *(const float4*)ap;
            float4 v1 = *(const float4*)(ap + 4);
            unsigned pa[4];
            pa[0] = pkbf(v0.x * ic, v0.y * ic);
            pa[1] = pkbf(v0.z * ic, v0.w * ic);
            pa[2] = pkbf(v1.x * ic, v1.y * ic);
            pa[3] = pkbf(v1.z * ic, v1.w * ic);
            *(uint4*)(SH + r * 296 + 128 + unit * 8) = *(uint4*)pa;
        }
        if (cseg < 4) {
            short8 z;
            #pragma unroll
            for (int k = 0; k < 8; ++k) z[k] = 0;
            if (cseg == 0) z[0] = (short)f2bf(post[n]);  // k=256
            *(short8*)(SH + r * 296 + 256 + cseg * 8) = z;
        }
    }
    __syncthreads();

    int w = t >> 6, lane = t & 63, q = lane >> 4, m = lane & 15;

    floatx4 acc[4] = {};
    #pragma unroll
    for (int c = 0; c < 9; ++c) {
        short8 b = *(const short8*)(W1p + ((size_t)(c * 8 + w) * 64 + lane) * 8);
        #pragma unroll
        for (int g2 = 0; g2 < 4; ++g2) {
            short8 a = *(const short8*)(SH + (g2 * 16 + m) * 296 + c * 32 + q * 8);
            acc[g2] = __builtin_amdgcn_mfma_f32_16x16x32_bf16(a, b, acc[g2], 0, 0, 0);
        }
    }
    // Ms is a separate region: no barrier needed before writing it.
    {
        int col = w * 16 + m;
        float bv = b1[col];
        #pragma unroll
        for (int g2 = 0; g2 < 4; ++g2) {
            unsigned p01 = pkbf(swishf(acc[g2][0] + bv), swishf(acc[g2][1] + bv));
            unsigned p23 = pkbf(swishf(acc[g2][2] + bv), swishf(acc[g2][3] + bv));
            int base = g2 * 16 + q * 4;
            Msh[(base + 0) * 136 + col] = (unsigned short)p01;
            Msh[(base + 1) * 136 + col] = (unsigned short)(p01 >> 16);
            Msh[(base + 2) * 136 + col] = (unsigned short)p23;
            Msh[(base + 3) * 136 + col] = (unsigned short)(p23 >> 16);
        }
    }
    __syncthreads();

    floatx4 acc2[4] = {};
    #pragma unroll
    for (int c = 0; c < 4; ++c) {
        short8 b = *(const short8*)(W2p + ((size_t)(c * 8 + w) * 64 + lane) * 8);
        #pragma unroll
        for (int g2 = 0; g2 < 4; ++g2) {
            short8 a = *(const short8*)(Msh + (g2 * 16 + m) * 136 + c * 32 + q * 8);
            acc2[g2] = __builtin_amdgcn_mfma_f32_16x16x32_bf16(a, b, acc2[g2], 0, 0, 0);
        }
    }

    // ---- epilogue: residual from LDS A region, fused stats, hraw bf16 write,
    //      zero agg slice
    int bidx = n0 >> 12;
    int col = w * 16 + m;
    float bv = b2[col];
    float s = 0.f, s2 = 0.f;
    #pragma unroll
    for (int g2 = 0; g2 < 4; ++g2) {
        #pragma unroll
        for (int r = 0; r < 4; ++r) {
            int row = g2 * 16 + q * 4 + r;
            float res = bf2f(SH[row * 296 + col]);   // staged normalized h
            float hv = res + swishf(acc2[g2][r] + bv);
            hraw[(size_t)(n0 + row) * 128 + col] = f2bf(hv);
            s += hv; s2 += hv * hv;
        }
    }
    s  += __shfl_xor(s, 16);  s  += __shfl_xor(s, 32);
    s2 += __shfl_xor(s2, 16); s2 += __shfl_xor(s2, 32);
    if (q == 0) {
        atomicAdd(&stats[bidx * 128 + col], s);
        atomicAdd(&stats[(NB + bidx) * 128 + col], s2);
    }
    {   // zero agg slice for next layer
        int r = t & 63, cseg = t >> 6;
        float4 z = make_float4(0.f, 0.f, 0.f, 0.f);
        #pragma unroll
        for (int j = 0; j < 4; ++j)
            *(float4*)(agg + (size_t)(n0 + r) * 128 + cseg * 16 + j * 4) = z;
    }
}

// ---------------------------------------------------------------------------
// Conv head: 4 nodes/block, one wave per node; normalizes hraw inline
// (final-layer norm folded here).
__global__ __launch_bounds__(256) void conv_kernel(
    const unsigned short* __restrict__ hraw, const float* __restrict__ stats,
    const float* __restrict__ u,
    const float* __restrict__ Wc1, const float* __restrict__ bc1,
    const float* __restrict__ Wc2, const float* __restrict__ bc2,
    float* __restrict__ out)
{
    __shared__ float hs[4][128];
    __shared__ float c1[4][8 * 40];
    int w = threadIdx.x >> 6, lane = threadIdx.x & 63;
    int n = blockIdx.x * 4 + w;
    int b = n >> 12;
    #pragma unroll
    for (int h2 = 0; h2 < 2; ++h2) {
        int c = lane + h2 * 64;
        float s1 = stats[b * 128 + c] * (1.f / 4096.f);
        float s2 = stats[(NB + b) * 128 + c] * (1.f / 4096.f);
        float rs = rsqrtf(s2 - s1 * s1 + 1e-5f);
        hs[w][c] = (bf2f(hraw[(size_t)n * 128 + c]) - s1) * rs;
    }
    __syncthreads();
    for (int idx = lane; idx < 304; idx += 64) {
        int o = idx / 38, p = idx % 38;
        float s = bc1[o];
        #pragma unroll
        for (int k = 0; k < 16; ++k) s += hs[w][p * 3 + k] * Wc1[o * 16 + k];
        c1[w][o * 40 + p] = swishf(s);
    }
    __syncthreads();
    if (lane < TW) {
        float s = bc2[0];
        #pragma unroll
        for (int o = 0; o < 8; ++o)
            for (int k = 0; k < 14; ++k)
                s += c1[w][o * 40 + lane + k] * Wc2[o * 14 + k];
        float dt_cum = (float)(lane + 1) * (4.0f / 250.0f);
        out[n * TW + lane] = u[n * 25 + 24] + dt_cum * s;
    }
}

// ---------------------------------------------------------------------------
extern "C" void kernel_launch(void* const* d_in, const int* in_sizes, int n_in,
                              void* d_out, int out_size, void* d_ws, size_t ws_size,
                              hipStream_t stream)
{
    const float* u   = (const float*)d_in[0];
    const float* pos = (const float*)d_in[1];
    const int*   ei  = (const int*)d_in[2];
    const float* We1 = (const float*)d_in[4];
    const float* be1 = (const float*)d_in[5];
    const float* We2 = (const float*)d_in[6];
    const float* be2 = (const float*)d_in[7];
    const float* Wm1 = (const float*)d_in[8];
    const float* bm1 = (const float*)d_in[9];
    const float* Wm2 = (const float*)d_in[10];
    const float* bm2 = (const float*)d_in[11];
    const float* Wu1 = (const float*)d_in[12];
    const float* bu1 = (const float*)d_in[13];
    const float* Wu2 = (const float*)d_in[14];
    const float* bu2 = (const float*)d_in[15];
    const float* Wc1 = (const float*)d_in[16];
    const float* bc1 = (const float*)d_in[17];
    const float* Wc2 = (const float*)d_in[18];
    const float* bc2 = (const float*)d_in[19];
    float* out = (float*)d_out;

    char* base = (char*)d_ws;
    size_t off = 0;
    auto alloc = [&](size_t bytes) -> char* {
        char* r = base + off;
        off = (off + bytes + 511) & ~(size_t)511;
        return r;
    };
    unsigned short* hraw   = (unsigned short*)alloc((size_t)N_NODES * 128 * 2);
    unsigned short* h_bf   = (unsigned short*)alloc((size_t)N_NODES * 128 * 2);
    float*          agg    = (float*)alloc((size_t)N_NODES * 128 * 4);
    float*          At     = (float*)alloc((size_t)N_NODES * 128 * 4);
    float*          As     = (float*)alloc((size_t)N_NODES * 128 * 4);
    float*          posx   = (float*)alloc(N_NODES * 4);
    float*          post   = (float*)alloc(N_NODES * 4);
    unsigned short* feat   = (unsigned short*)alloc((size_t)N_NODES * 32 * 2);
    float*          stats  = (float*)alloc(2 * NB * 128 * 4);
    int*            deg    = (int*)alloc(N_NODES * 4);
    int*            cursor = (int*)alloc(N_NODES * 4);
    int*            src_s  = (int*)alloc((size_t)N_EDGES * 4);
    int*            tgt_s  = (int*)alloc((size_t)N_EDGES * 4);
    unsigned short* Wcat1p = (unsigned short*)alloc((size_t)6 * 5 * 16 * 64 * 8 * 2);
    unsigned short* Wm2p   = (unsigned short*)alloc((size_t)6 * 4 * 4096 * 2);
    unsigned short* Wu1p   = (unsigned short*)alloc((size_t)6 * 9 * 4096 * 2);
    unsigned short* Wu2p   = (unsigned short*)alloc((size_t)6 * 4 * 4096 * 2);
    (void)ws_size;

    const int* srcp = ei;
    const int* tgtp = ei + N_EDGES;

    init_kernel<<<N_NODES / 256, 256, 0, stream>>>(pos, u, posx, post, feat);
    hipMemsetAsync(deg, 0, N_NODES * sizeof(int), stream);
    deg_kernel<<<N_EDGES / 256, 256, 0, stream>>>(tgtp, deg);
    scan_kernel<<<1, 1024, 0, stream>>>(deg, cursor);
    scatter_kernel<<<N_EDGES / 256, 256, 0, stream>>>(srcp, tgtp, cursor, src_s, tgt_s);
    encoder_kernel<<<N_NODES / 64, 256, 0, stream>>>(u, posx, post, We1, be1, We2, be2,
                                                     hraw, agg);
    {
        pack_cat_kernel<<<120, 256, 0, stream>>>(Wm1, Wcat1p);
        int tot1 = 6 * 9 * 512;
        int tot2 = 6 * 4 * 512;
        pack_kernel<<<(tot2 + 255) / 256, 256, 0, stream>>>(Wm2, Wm2p, 128, 4, tot2);
        pack_kernel<<<(tot1 + 255) / 256, 256, 0, stream>>>(Wu1, Wu1p, 257, 9, tot1);
        pack_kernel<<<(tot2 + 255) / 256, 256, 0, stream>>>(Wu2, Wu2p, 128, 4, tot2);
    }

    for (int l = 0; l < 6; ++l) {
        premsg_kernel<<<N_NODES / 64, 512, 0, stream>>>(
            hraw, stats, (l > 0) ? 1 : 0, feat,
            Wcat1p + (size_t)l * 5 * 16 * 64 * 8, bm1 + l * 128,
            h_bf, At, As);
        message_kernel<<<N_EDGES / 64, 256, 0, stream>>>(
            At, As, src_s, tgt_s,
            Wm2p + (size_t)l * 4 * 4096, bm2 + l * 128, agg, stats);
        update_kernel<<<N_NODES / 64, 512, 0, stream>>>(
            hraw, h_bf, agg, deg, post,
            Wu1p + (size_t)l * 9 * 4096, bu1 + l * 128,
            Wu2p + (size_t)l * 4 * 4096, bu2 + l * 128, stats);
    }

    conv_kernel<<<N_NODES / 4, 256, 0, stream>>>(hraw, stats, u, Wc1, bc1, Wc2, bc2, out);
}

// Round 4
// 637.586 us; speedup vs baseline: 1.1320x; 1.1320x over previous
//
#include <hip/hip_runtime.h>
#include <stdint.h>

#define N_NODES 32768
#define N_EDGES 262144
#define NB 8
#define TW 25

typedef __attribute__((ext_vector_type(8))) short short8;
typedef __attribute__((ext_vector_type(4))) float floatx4;

#if defined(__has_builtin)
#if __has_builtin(__builtin_amdgcn_cvt_pk_bf16_f32)
#define HAVE_CVT_PK_BF16 1
#endif
#endif

// swish via HW approximate reciprocal (v_rcp_f32): ~1-ulp rel error,
// far below bf16 quantization; avoids the ~10-instr IEEE divide sequence.
__device__ __forceinline__ float swishf(float x) {
    return x * __builtin_amdgcn_rcpf(1.0f + __expf(-x));
}

__device__ __forceinline__ unsigned short f2bf(float x) {
    union { float f; unsigned u; } v; v.f = x;
    unsigned r = v.u + 0x7FFFu + ((v.u >> 16) & 1u);
    return (unsigned short)(r >> 16);
}
// packed f32x2 -> bf16x2 (low = a, high = b); HW v_cvt_pk_bf16_f32 on gfx950
__device__ __forceinline__ unsigned pkbf(float a, float b) {
#ifdef HAVE_CVT_PK_BF16
    typedef __attribute__((ext_vector_type(2))) __bf16 bf16x2;
    union { bf16x2 v; unsigned u; } cv;
    cv.v = __builtin_amdgcn_cvt_pk_bf16_f32(a, b);
    return cv.u;
#else
    return (unsigned)f2bf(a) | ((unsigned)f2bf(b) << 16);
#endif
}
__device__ __forceinline__ float bf2f(unsigned short b) {
    union { unsigned u; float f; } v; v.u = ((unsigned)b) << 16; return v.f;
}
// bf16x2 word -> two f32 (lo = bits<<16, hi = bits&0xffff0000)
__device__ __forceinline__ float bflo(unsigned w) {
    union { unsigned u; float f; } v; v.u = w << 16; return v.f;
}
__device__ __forceinline__ float bfhi(unsigned w) {
    union { unsigned u; float f; } v; v.u = w & 0xffff0000u; return v.f;
}

// ---------------------------------------------------------------------------
// init: posx/post + per-node static feature tail feat[32] = [u(25), posx, post, 0x5] bf16
__global__ void init_kernel(const float* __restrict__ pos, const float* __restrict__ u,
                            float* __restrict__ posx, float* __restrict__ post,
                            unsigned short* __restrict__ feat) {
    int i = blockIdx.x * 256 + threadIdx.x;
    if (i < N_NODES) {
        float pt = pos[i * 2 + 0] * 0.25f;
        float px = pos[i * 2 + 1] * 0.0625f;
        post[i] = pt;
        posx[i] = px;
        unsigned short f[32];
        #pragma unroll
        for (int k = 0; k < 25; ++k) f[k] = f2bf(u[(size_t)i * 25 + k]);
        f[25] = f2bf(px);
        f[26] = f2bf(pt);
        #pragma unroll
        for (int k = 27; k < 32; ++k) f[k] = 0;
        #pragma unroll
        for (int j = 0; j < 4; ++j)
            *(uint4*)(feat + (size_t)i * 32 + j * 8) = *(uint4*)&f[j * 8];
    }
}

__global__ void deg_kernel(const int* __restrict__ tgt, int* __restrict__ deg) {
    int i = blockIdx.x * 256 + threadIdx.x;
    if (i < N_EDGES) atomicAdd(&deg[tgt[i]], 1);
}

// exclusive scan of deg -> cursor, single block
__global__ __launch_bounds__(1024) void scan_kernel(const int* __restrict__ deg,
                                                    int* __restrict__ cursor) {
    __shared__ int ps[1024];
    int t = threadIdx.x;
    int base = t * 32;
    int tot = 0;
    for (int i = 0; i < 32; ++i) tot += deg[base + i];
    ps[t] = tot;
    __syncthreads();
    for (int off = 1; off < 1024; off <<= 1) {
        int v = (t >= off) ? ps[t - off] : 0;
        __syncthreads();
        ps[t] += v;
        __syncthreads();
    }
    int run = ps[t] - tot;
    for (int i = 0; i < 32; ++i) {
        cursor[base + i] = run;
        run += deg[base + i];
    }
}

// tgt-sorted edge arrays directly
__global__ void scatter_kernel(const int* __restrict__ src, const int* __restrict__ tgt,
                               int* __restrict__ cursor,
                               int* __restrict__ src_s, int* __restrict__ tgt_s) {
    int i = blockIdx.x * 256 + threadIdx.x;
    if (i < N_EDGES) {
        int tg = tgt[i];
        int p = atomicAdd(&cursor[tg], 1);
        src_s[p] = src[i];
        tgt_s[p] = tg;
    }
}

// ---------------------------------------------------------------------------
// Pack weight into MFMA B-frag order: frag id = ((l*Kc + c)*8 + t8)*64 + lane,
// lane holds B[k=c*32+(lane>>4)*8+j][n=t8*16+(lane&15)], j=0..7.
__global__ __launch_bounds__(256) void pack_kernel(const float* __restrict__ W,
                                                   unsigned short* __restrict__ Wp,
                                                   int Kreal, int Kc, int total) {
    int id = blockIdx.x * 256 + threadIdx.x;
    if (id >= total) return;
    int lane = id & 63;
    int t8 = (id >> 6) & 7;
    int rest = id >> 9;
    int c = rest % Kc;
    int l = rest / Kc;
    int n = t8 * 16 + (lane & 15);
    int kb = c * 32 + (lane >> 4) * 8;
    short8 v;
    #pragma unroll
    for (int j = 0; j < 8; ++j) {
        int k = kb + j;
        float x = (k < Kreal) ? W[((size_t)l * Kreal + k) * 128 + n] : 0.f;
        v[j] = (short)f2bf(x);
    }
    *(short8*)(Wp + (size_t)id * 8) = v;
}

// Pack the message GEMM1 weight (283x128 per layer) into the per-node
// projection form Wcat (160 x 256): cols 0..127 -> A_t, 128..255 -> A_s.
//   k<128   : h rows      (A_t: rows 0..127;  A_s: rows 128..255)
//   k=128..152: u_diff rows 256..280   (A_s negated)
//   k=153   : p_diff row 281           (A_s negated)
//   k=154   : var_i row 282            (A_s zero)
// frag id = ((l*5 + c)*16 + tile)*64 + lane; 6*5*16*64 = 30720 ids total.
__global__ __launch_bounds__(256) void pack_cat_kernel(const float* __restrict__ Wm1,
                                                       unsigned short* __restrict__ Wp) {
    int id = blockIdx.x * 256 + threadIdx.x;
    if (id >= 30720) return;
    int lane = id & 63;
    int tile = (id >> 6) & 15;
    int rest = id >> 10;
    int c = rest % 5;
    int l = rest / 5;
    int n = tile * 16 + (lane & 15);
    int col = n & 127;
    bool isT = n < 128;
    int kb = c * 32 + (lane >> 4) * 8;
    const float* W = Wm1 + (size_t)l * 283 * 128;
    short8 v;
    #pragma unroll
    for (int j = 0; j < 8; ++j) {
        int k = kb + j;
        float x = 0.f;
        if (k < 128) {
            x = W[(size_t)(isT ? k : 128 + k) * 128 + col];
        } else if (k < 155) {
            int row = 256 + (k - 128);   // 256..282
            x = W[(size_t)row * 128 + col];
            if (!isT) x = (row == 282) ? 0.f : -x;
        }
        v[j] = (short)f2bf(x);
    }
    *(short8*)(Wp + (size_t)id * 8) = v;
}

// ---------------------------------------------------------------------------
// Encoder; writes hraw (bf16, unnormalized h) and zeroes this block's agg slice
__global__ __launch_bounds__(256) void encoder_kernel(
    const float* __restrict__ u, const float* __restrict__ posx,
    const float* __restrict__ post,
    const float* __restrict__ We1, const float* __restrict__ be1,
    const float* __restrict__ We2, const float* __restrict__ be2,
    unsigned short* __restrict__ hraw, float* __restrict__ agg)
{
    __shared__ __align__(16) float As_[64 * 36];
    __shared__ __align__(16) float Ws[32 * 128];
    __shared__ __align__(16) float Ms[64 * 128];

    int t = threadIdx.x;
    int n0 = blockIdx.x * 64;
    int rg = t >> 5, cg = t & 31;

    {   // zero agg slice
        int r = t & 63, cseg = t >> 6;
        float4 z = make_float4(0.f, 0.f, 0.f, 0.f);
        #pragma unroll
        for (int j = 0; j < 8; ++j)
            *(float4*)(agg + (size_t)(n0 + r) * 128 + cseg * 32 + j * 4) = z;
    }

    float acc[8][4] = {};
    {
        int kk = t >> 3, cb = (t & 7) * 16;
        #pragma unroll
        for (int j = 0; j < 4; ++j) {
            float4 w = make_float4(0.f, 0.f, 0.f, 0.f);
            if (kk < 27) w = *(const float4*)&We1[kk * 128 + cb + j * 4];
            *(float4*)&Ws[kk * 128 + cb + j * 4] = w;
        }
        int el = t >> 2, kb = (t & 3) * 8, n = n0 + el;
        float v[8];
        #pragma unroll
        for (int j = 0; j < 8; ++j) {
            int k = kb + j;
            float x = 0.f;
            if (k < 25) x = u[n * 25 + k];
            else if (k == 25) x = posx[n];
            else if (k == 26) x = post[n];
            v[j] = x;
        }
        #pragma unroll
        for (int j = 0; j < 8; j += 4)
            *(float4*)&As_[el * 36 + kb + j] = make_float4(v[j], v[j+1], v[j+2], v[j+3]);
        __syncthreads();
        #pragma unroll 4
        for (int kk2 = 0; kk2 < 32; ++kk2) {
            float4 b = *(const float4*)&Ws[kk2 * 128 + cg * 4];
            float a[8];
            #pragma unroll
            for (int i = 0; i < 8; ++i) a[i] = As_[(rg * 8 + i) * 36 + kk2];
            #pragma unroll
            for (int i = 0; i < 8; ++i) {
                acc[i][0] += a[i] * b.x; acc[i][1] += a[i] * b.y;
                acc[i][2] += a[i] * b.z; acc[i][3] += a[i] * b.w;
            }
        }
        __syncthreads();
    }
    {
        float4 b1 = *(const float4*)&be1[cg * 4];
        #pragma unroll
        for (int i = 0; i < 8; ++i) {
            float4 m;
            m.x = swishf(acc[i][0] + b1.x);
            m.y = swishf(acc[i][1] + b1.y);
            m.z = swishf(acc[i][2] + b1.z);
            m.w = swishf(acc[i][3] + b1.w);
            *(float4*)&Ms[(rg * 8 + i) * 128 + cg * 4] = m;
        }
        __syncthreads();
    }
    float acc2[8][4] = {};
    for (int k0 = 0; k0 < 128; k0 += 32) {
        int kk = t >> 3, cb = (t & 7) * 16;
        #pragma unroll
        for (int j = 0; j < 4; ++j)
            *(float4*)&Ws[kk * 128 + cb + j * 4] =
                *(const float4*)&We2[(k0 + kk) * 128 + cb + j * 4];
        __syncthreads();
        #pragma unroll 4
        for (int kk2 = 0; kk2 < 32; ++kk2) {
            float4 b = *(const float4*)&Ws[kk2 * 128 + cg * 4];
            float a[8];
            #pragma unroll
            for (int i = 0; i < 8; ++i) a[i] = Ms[(rg * 8 + i) * 128 + (k0 + kk2)];
            #pragma unroll
            for (int i = 0; i < 8; ++i) {
                acc2[i][0] += a[i] * b.x; acc2[i][1] += a[i] * b.y;
                acc2[i][2] += a[i] * b.z; acc2[i][3] += a[i] * b.w;
            }
        }
        __syncthreads();
    }
    {
        float4 b2 = *(const float4*)&be2[cg * 4];
        #pragma unroll
        for (int i = 0; i < 8; ++i) {
            int n = n0 + rg * 8 + i;
            float4 o;
            o.x = swishf(acc2[i][0] + b2.x);
            o.y = swishf(acc2[i][1] + b2.y);
            o.z = swishf(acc2[i][2] + b2.z);
            o.w = swishf(acc2[i][3] + b2.w);
            uint2 pk;
            pk.x = pkbf(o.x, o.y);
            pk.y = pkbf(o.z, o.w);
            *(uint2*)(hraw + (size_t)n * 128 + cg * 4) = pk;
        }
    }
}

// ---------------------------------------------------------------------------
// Per-node pre-message projection (replaces per-edge GEMM1):
//   h_norm = (hraw - mean)/std  (skip when donorm==0),   written to h_bf
//   [A_t | A_s] = [h_norm(128) | feat(32)] @ Wcat(160x256)   (+ b1 on A_t)
// At/As stored bf16 (halves the message kernel's gather traffic).
// 64 nodes/block, 512 threads (8 waves), wave w owns col tiles w (A_t) and 8+w (A_s).
__global__ __launch_bounds__(512, 4) void premsg_kernel(
    const unsigned short* __restrict__ hraw,
    const float* __restrict__ stats, int donorm,
    const unsigned short* __restrict__ feat,
    const unsigned short* __restrict__ Wp, const float* __restrict__ b1,
    unsigned short* __restrict__ h_bf,
    unsigned short* __restrict__ At, unsigned short* __restrict__ As)
{
    __shared__ __align__(16) unsigned short A[64 * 168];   // 21504 B
    __shared__ float mean_s[128];
    __shared__ float rstd_s[128];

    int t = threadIdx.x;
    int n0 = blockIdx.x * 64;
    int bidx = n0 >> 12;

    if (t < 128) {
        float mn = 0.f, rs = 1.f;
        if (donorm) {
            float s1 = stats[bidx * 128 + t] * (1.f / 4096.f);
            float s2 = stats[(NB + bidx) * 128 + t] * (1.f / 4096.f);
            mn = s1;
            rs = rsqrtf(s2 - s1 * s1 + 1e-5f);
        }
        mean_s[t] = mn;
        rstd_s[t] = rs;
    }
    __syncthreads();

    {   // stage [h_norm | feat] into LDS; also write h_bf
        int r = t & 63, cseg = t >> 6;
        int n = n0 + r;
        uint4 raw0 = *(const uint4*)(hraw + (size_t)n * 128 + cseg * 16);
        uint4 raw1 = *(const uint4*)(hraw + (size_t)n * 128 + cseg * 16 + 8);
        unsigned pk[8];
        #pragma unroll
        for (int j = 0; j < 8; ++j) {
            unsigned word = (j < 4) ? ((const unsigned*)&raw0)[j]
                                    : ((const unsigned*)&raw1)[j - 4];
            int c0 = cseg * 16 + j * 2;
            float v0 = (bf2f((unsigned short)(word & 0xffffu)) - mean_s[c0]) * rstd_s[c0];
            float v1 = (bf2f((unsigned short)(word >> 16)) - mean_s[c0 + 1]) * rstd_s[c0 + 1];
            pk[j] = pkbf(v0, v1);
        }
        *(uint4*)(A + r * 168 + cseg * 16)     = *(uint4*)&pk[0];
        *(uint4*)(A + r * 168 + cseg * 16 + 8) = *(uint4*)&pk[4];
        *(uint4*)(h_bf + (size_t)n * 128 + cseg * 16)     = *(uint4*)&pk[0];
        *(uint4*)(h_bf + (size_t)n * 128 + cseg * 16 + 8) = *(uint4*)&pk[4];
        if (cseg < 2) {
            uint4 f0 = *(const uint4*)(feat + (size_t)n * 32 + cseg * 16);
            uint4 f1 = *(const uint4*)(feat + (size_t)n * 32 + cseg * 16 + 8);
            *(uint4*)(A + r * 168 + 128 + cseg * 16)     = f0;
            *(uint4*)(A + r * 168 + 128 + cseg * 16 + 8) = f1;
        }
    }
    __syncthreads();

    int w = t >> 6, lane = t & 63, q = lane >> 4, m = lane & 15;
    floatx4 accT[4] = {};
    floatx4 accS[4] = {};
    #pragma unroll
    for (int c = 0; c < 5; ++c) {
        short8 bT = *(const short8*)(Wp + ((size_t)(c * 16 + w) * 64 + lane) * 8);
        short8 bS = *(const short8*)(Wp + ((size_t)(c * 16 + 8 + w) * 64 + lane) * 8);
        #pragma unroll
        for (int g2 = 0; g2 < 4; ++g2) {
            short8 a = *(const short8*)(A + (g2 * 16 + m) * 168 + c * 32 + q * 8);
            accT[g2] = __builtin_amdgcn_mfma_f32_16x16x32_bf16(a, bT, accT[g2], 0, 0, 0);
            accS[g2] = __builtin_amdgcn_mfma_f32_16x16x32_bf16(a, bS, accS[g2], 0, 0, 0);
        }
    }
    int col = w * 16 + m;
    float bv = b1[col];
    #pragma unroll
    for (int g2 = 0; g2 < 4; ++g2) {
        #pragma unroll
        for (int r = 0; r < 4; ++r) {
            int row = g2 * 16 + q * 4 + r;
            At[(size_t)(n0 + row) * 128 + col] = f2bf(accT[g2][r] + bv);
            As[(size_t)(n0 + row) * 128 + col] = f2bf(accS[g2][r]);
        }
    }
}

// ---------------------------------------------------------------------------
// Message: register-A structure, bf16 gathers, full occupancy.
// 64 tgt-sorted edges/block, 256 threads (4 waves); wave w owns edges
// w*16..w*16+16 x ALL 128 output cols. Each lane (q,m) computes its MFMA
// A-frag in registers: A[row=m][k=c*32+q*8+j] = swish(At[tgt]+As[src]).
// LDS: only Cs (epilogue->reduction, per-wave-private region, no barrier).
// __launch_bounds__(256,8): 8 blocks/CU = 32 waves/CU (VGPR<=64, LDS 17.4KB).
__global__ __launch_bounds__(256, 8) void message_kernel(
    const unsigned short* __restrict__ At, const unsigned short* __restrict__ As,
    const int* __restrict__ src_s, const int* __restrict__ tgt_s,
    const unsigned short* __restrict__ W2p, const float* __restrict__ b2,
    float* __restrict__ agg, float* __restrict__ stats)
{
    __shared__ __align__(16) unsigned short Cs[64 * 132];   // 16896 B
    __shared__ int tgtS[64];

    int t = threadIdx.x;
    int e0 = blockIdx.x * 64;
    if (blockIdx.x == 0) {  // zero stats for this layer (t*8 covers 2048 floats)
        float4 z = make_float4(0.f, 0.f, 0.f, 0.f);
        *(float4*)&stats[t * 8] = z;
        *(float4*)&stats[t * 8 + 4] = z;
    }
    if (t < 64) tgtS[t] = tgt_s[e0 + t];
    __syncthreads();

    int w = t >> 6, lane = t & 63, q = lane >> 4, m = lane & 15;
    int erow = w * 16 + m;           // this lane's edge (A-frag row)
    int e = e0 + erow;
    int gg = tgtS[erow];
    int ss = src_s[e];

    // ---- gather At/As bf16 k-slices (8 x 16B loads; issue all up front)
    const unsigned short* atp = At + (size_t)gg * 128 + q * 8;
    const unsigned short* asp = As + (size_t)ss * 128 + q * 8;
    uint4 wa[4], wb[4];
    #pragma unroll
    for (int c = 0; c < 4; ++c) {
        wa[c] = *(const uint4*)(atp + c * 32);
        wb[c] = *(const uint4*)(asp + c * 32);
    }
    // ---- A-frags in registers: unpack + add + swish + repack
    short8 af[4];
    #pragma unroll
    for (int c = 0; c < 4; ++c) {
        const unsigned* ua = (const unsigned*)&wa[c];
        const unsigned* ub = (const unsigned*)&wb[c];
        union { unsigned u[4]; short8 s; } pk_;
        #pragma unroll
        for (int j = 0; j < 4; ++j) {
            float lo = swishf(bflo(ua[j]) + bflo(ub[j]));
            float hi = swishf(bfhi(ua[j]) + bfhi(ub[j]));
            pk_.u[j] = pkbf(lo, hi);
        }
        af[c] = pk_.s;
    }

    // ---- GEMM2: 4 K-chunks x 8 col-tiles, B-frags straight from global (L1/L2)
    floatx4 acc[8] = {};
    #pragma unroll
    for (int c = 0; c < 4; ++c) {
        #pragma unroll
        for (int t8 = 0; t8 < 8; ++t8) {
            short8 b = *(const short8*)(W2p + ((size_t)(c * 8 + t8) * 64 + lane) * 8);
            acc[t8] = __builtin_amdgcn_mfma_f32_16x16x32_bf16(af[c], b, acc[t8], 0, 0, 0);
        }
    }

    // ---- epilogue: swish + write per-wave Cs region (rows w*16..w*16+16)
    #pragma unroll
    for (int t8 = 0; t8 < 8; ++t8) {
        float bv = b2[t8 * 16 + m];
        unsigned p01 = pkbf(swishf(acc[t8][0] + bv), swishf(acc[t8][1] + bv));
        unsigned p23 = pkbf(swishf(acc[t8][2] + bv), swishf(acc[t8][3] + bv));
        int rb = (w * 16 + q * 4) * 132 + t8 * 16 + m;
        Cs[rb]           = (unsigned short)p01;
        Cs[rb + 132]     = (unsigned short)(p01 >> 16);
        Cs[rb + 2 * 132] = (unsigned short)p23;
        Cs[rb + 3 * 132] = (unsigned short)(p23 >> 16);
    }

    // ---- reduction over this wave's 16 rows (wave-synchronous: same wave wrote
    //      this Cs region; program order + lgkmcnt gives the ordering)
    {
        int r0 = w * 16;
        int col0 = lane;                 // cols lane and lane+64
        float run0 = 0.f, run1 = 0.f;
        int prev = tgtS[r0];
        bool atStart = true;
        #pragma unroll 4
        for (int i = 0; i < 16; ++i) {
            int tg = tgtS[r0 + i];
            if (tg != prev) {
                float* d0 = &agg[(size_t)prev * 128 + col0];
                if (atStart) { atomicAdd(d0, run0); atomicAdd(d0 + 64, run1); }
                else         { d0[0] = run0;        d0[64] = run1; }
                run0 = 0.f; run1 = 0.f; prev = tg; atStart = false;
            }
            run0 += bf2f(Cs[(r0 + i) * 132 + col0]);
            run1 += bf2f(Cs[(r0 + i) * 132 + col0 + 64]);
        }
        float* d0 = &agg[(size_t)prev * 128 + col0];
        atomicAdd(d0, run0);
        atomicAdd(d0 + 64, run1);
    }
}

// ---------------------------------------------------------------------------
// Update MLP: unchanged. Residual from staged A region; writes pre-norm hraw
// + fused batch stats; zeroes agg slice for next layer.
__global__ __launch_bounds__(512, 4) void update_kernel(
    unsigned short* __restrict__ hraw, const unsigned short* __restrict__ h_bf,
    float* __restrict__ agg, const int* __restrict__ deg,
    const float* __restrict__ post,
    const unsigned short* __restrict__ W1p, const float* __restrict__ b1,
    const unsigned short* __restrict__ W2p, const float* __restrict__ b2,
    float* __restrict__ stats)
{
    __shared__ __align__(16) unsigned short SH[64 * 296 + 64 * 136];  // 55296 B
    unsigned short* Msh = SH + 64 * 296;

    int t = threadIdx.x;
    int n0 = blockIdx.x * 64;

    // ---- stage A = [h_bf | agg/deg (bf16) | post-pad]: 8 threads/row
    {
        int r = t & 63, cseg = t >> 6;
        int n = n0 + r;
        const short8* hn = (const short8*)(h_bf + (size_t)n * 128);
        #pragma unroll
        for (int j = 0; j < 2; ++j) {
            int chunk = cseg * 2 + j;
            *(short8*)(SH + r * 296 + chunk * 8) = hn[chunk];
        }
        float ic = __builtin_amdgcn_rcpf(fmaxf((float)deg[n], 1.0f));
        #pragma unroll
        for (int j = 0; j < 2; ++j) {
            int unit = cseg * 2 + j;
            const float* ap = agg + (size_t)n * 128 + unit * 8;
            float4 v0 = *(const float4*)ap;
            float4 v1 = *(const float4*)(ap + 4);
            unsigned pa[4];
            pa[0] = pkbf(v0.x * ic, v0.y * ic);
            pa[1] = pkbf(v0.z * ic, v0.w * ic);
            pa[2] = pkbf(v1.x * ic, v1.y * ic);
            pa[3] = pkbf(v1.z * ic, v1.w * ic);
            *(uint4*)(SH + r * 296 + 128 + unit * 8) = *(uint4*)pa;
        }
        if (cseg < 4) {
            short8 z;
            #pragma unroll
            for (int k = 0; k < 8; ++k) z[k] = 0;
            if (cseg == 0) z[0] = (short)f2bf(post[n]);  // k=256
            *(short8*)(SH + r * 296 + 256 + cseg * 8) = z;
        }
    }
    __syncthreads();

    int w = t >> 6, lane = t & 63, q = lane >> 4, m = lane & 15;

    floatx4 acc[4] = {};
    #pragma unroll
    for (int c = 0; c < 9; ++c) {
        short8 b = *(const short8*)(W1p + ((size_t)(c * 8 + w) * 64 + lane) * 8);
        #pragma unroll
        for (int g2 = 0; g2 < 4; ++g2) {
            short8 a = *(const short8*)(SH + (g2 * 16 + m) * 296 + c * 32 + q * 8);
            acc[g2] = __builtin_amdgcn_mfma_f32_16x16x32_bf16(a, b, acc[g2], 0, 0, 0);
        }
    }
    // Ms is a separate region: no barrier needed before writing it.
    {
        int col = w * 16 + m;
        float bv = b1[col];
        #pragma unroll
        for (int g2 = 0; g2 < 4; ++g2) {
            unsigned p01 = pkbf(swishf(acc[g2][0] + bv), swishf(acc[g2][1] + bv));
            unsigned p23 = pkbf(swishf(acc[g2][2] + bv), swishf(acc[g2][3] + bv));
            int base = g2 * 16 + q * 4;
            Msh[(base + 0) * 136 + col] = (unsigned short)p01;
            Msh[(base + 1) * 136 + col] = (unsigned short)(p01 >> 16);
            Msh[(base + 2) * 136 + col] = (unsigned short)p23;
            Msh[(base + 3) * 136 + col] = (unsigned short)(p23 >> 16);
        }
    }
    __syncthreads();

    floatx4 acc2[4] = {};
    #pragma unroll
    for (int c = 0; c < 4; ++c) {
        short8 b = *(const short8*)(W2p + ((size_t)(c * 8 + w) * 64 + lane) * 8);
        #pragma unroll
        for (int g2 = 0; g2 < 4; ++g2) {
            short8 a = *(const short8*)(Msh + (g2 * 16 + m) * 136 + c * 32 + q * 8);
            acc2[g2] = __builtin_amdgcn_mfma_f32_16x16x32_bf16(a, b, acc2[g2], 0, 0, 0);
        }
    }

    // ---- epilogue: residual from LDS A region, fused stats, hraw bf16 write,
    //      zero agg slice
    int bidx = n0 >> 12;
    int col = w * 16 + m;
    float bv = b2[col];
    float s = 0.f, s2 = 0.f;
    #pragma unroll
    for (int g2 = 0; g2 < 4; ++g2) {
        #pragma unroll
        for (int r = 0; r < 4; ++r) {
            int row = g2 * 16 + q * 4 + r;
            float res = bf2f(SH[row * 296 + col]);   // staged normalized h
            float hv = res + swishf(acc2[g2][r] + bv);
            hraw[(size_t)(n0 + row) * 128 + col] = f2bf(hv);
            s += hv; s2 += hv * hv;
        }
    }
    s  += __shfl_xor(s, 16);  s  += __shfl_xor(s, 32);
    s2 += __shfl_xor(s2, 16); s2 += __shfl_xor(s2, 32);
    if (q == 0) {
        atomicAdd(&stats[bidx * 128 + col], s);
        atomicAdd(&stats[(NB + bidx) * 128 + col], s2);
    }
    {   // zero agg slice for next layer
        int r = t & 63, cseg = t >> 6;
        float4 z = make_float4(0.f, 0.f, 0.f, 0.f);
        #pragma unroll
        for (int j = 0; j < 4; ++j)
            *(float4*)(agg + (size_t)(n0 + r) * 128 + cseg * 16 + j * 4) = z;
    }
}

// ---------------------------------------------------------------------------
// Conv head: 4 nodes/block, one wave per node; normalizes hraw inline
// (final-layer norm folded here).
__global__ __launch_bounds__(256) void conv_kernel(
    const unsigned short* __restrict__ hraw, const float* __restrict__ stats,
    const float* __restrict__ u,
    const float* __restrict__ Wc1, const float* __restrict__ bc1,
    const float* __restrict__ Wc2, const float* __restrict__ bc2,
    float* __restrict__ out)
{
    __shared__ float hs[4][128];
    __shared__ float c1[4][8 * 40];
    int w = threadIdx.x >> 6, lane = threadIdx.x & 63;
    int n = blockIdx.x * 4 + w;
    int b = n >> 12;
    #pragma unroll
    for (int h2 = 0; h2 < 2; ++h2) {
        int c = lane + h2 * 64;
        float s1 = stats[b * 128 + c] * (1.f / 4096.f);
        float s2 = stats[(NB + b) * 128 + c] * (1.f / 4096.f);
        float rs = rsqrtf(s2 - s1 * s1 + 1e-5f);
        hs[w][c] = (bf2f(hraw[(size_t)n * 128 + c]) - s1) * rs;
    }
    __syncthreads();
    for (int idx = lane; idx < 304; idx += 64) {
        int o = idx / 38, p = idx % 38;
        float s = bc1[o];
        #pragma unroll
        for (int k = 0; k < 16; ++k) s += hs[w][p * 3 + k] * Wc1[o * 16 + k];
        c1[w][o * 40 + p] = swishf(s);
    }
    __syncthreads();
    if (lane < TW) {
        float s = bc2[0];
        #pragma unroll
        for (int o = 0; o < 8; ++o)
            for (int k = 0; k < 14; ++k)
                s += c1[w][o * 40 + lane + k] * Wc2[o * 14 + k];
        float dt_cum = (float)(lane + 1) * (4.0f / 250.0f);
        out[n * TW + lane] = u[n * 25 + 24] + dt_cum * s;
    }
}

// ---------------------------------------------------------------------------
extern "C" void kernel_launch(void* const* d_in, const int* in_sizes, int n_in,
                              void* d_out, int out_size, void* d_ws, size_t ws_size,
                              hipStream_t stream)
{
    const float* u   = (const float*)d_in[0];
    const float* pos = (const float*)d_in[1];
    const int*   ei  = (const int*)d_in[2];
    const float* We1 = (const float*)d_in[4];
    const float* be1 = (const float*)d_in[5];
    const float* We2 = (const float*)d_in[6];
    const float* be2 = (const float*)d_in[7];
    const float* Wm1 = (const float*)d_in[8];
    const float* bm1 = (const float*)d_in[9];
    const float* Wm2 = (const float*)d_in[10];
    const float* bm2 = (const float*)d_in[11];
    const float* Wu1 = (const float*)d_in[12];
    const float* bu1 = (const float*)d_in[13];
    const float* Wu2 = (const float*)d_in[14];
    const float* bu2 = (const float*)d_in[15];
    const float* Wc1 = (const float*)d_in[16];
    const float* bc1 = (const float*)d_in[17];
    const float* Wc2 = (const float*)d_in[18];
    const float* bc2 = (const float*)d_in[19];
    float* out = (float*)d_out;

    char* base = (char*)d_ws;
    size_t off = 0;
    auto alloc = [&](size_t bytes) -> char* {
        char* r = base + off;
        off = (off + bytes + 511) & ~(size_t)511;
        return r;
    };
    unsigned short* hraw   = (unsigned short*)alloc((size_t)N_NODES * 128 * 2);
    unsigned short* h_bf   = (unsigned short*)alloc((size_t)N_NODES * 128 * 2);
    float*          agg    = (float*)alloc((size_t)N_NODES * 128 * 4);
    unsigned short* At     = (unsigned short*)alloc((size_t)N_NODES * 128 * 2);
    unsigned short* As     = (unsigned short*)alloc((size_t)N_NODES * 128 * 2);
    float*          posx   = (float*)alloc(N_NODES * 4);
    float*          post   = (float*)alloc(N_NODES * 4);
    unsigned short* feat   = (unsigned short*)alloc((size_t)N_NODES * 32 * 2);
    float*          stats  = (float*)alloc(2 * NB * 128 * 4);
    int*            deg    = (int*)alloc(N_NODES * 4);
    int*            cursor = (int*)alloc(N_NODES * 4);
    int*            src_s  = (int*)alloc((size_t)N_EDGES * 4);
    int*            tgt_s  = (int*)alloc((size_t)N_EDGES * 4);
    unsigned short* Wcat1p = (unsigned short*)alloc((size_t)6 * 5 * 16 * 64 * 8 * 2);
    unsigned short* Wm2p   = (unsigned short*)alloc((size_t)6 * 4 * 4096 * 2);
    unsigned short* Wu1p   = (unsigned short*)alloc((size_t)6 * 9 * 4096 * 2);
    unsigned short* Wu2p   = (unsigned short*)alloc((size_t)6 * 4 * 4096 * 2);
    (void)ws_size;

    const int* srcp = ei;
    const int* tgtp = ei + N_EDGES;

    init_kernel<<<N_NODES / 256, 256, 0, stream>>>(pos, u, posx, post, feat);
    hipMemsetAsync(deg, 0, N_NODES * sizeof(int), stream);
    deg_kernel<<<N_EDGES / 256, 256, 0, stream>>>(tgtp, deg);
    scan_kernel<<<1, 1024, 0, stream>>>(deg, cursor);
    scatter_kernel<<<N_EDGES / 256, 256, 0, stream>>>(srcp, tgtp, cursor, src_s, tgt_s);
    encoder_kernel<<<N_NODES / 64, 256, 0, stream>>>(u, posx, post, We1, be1, We2, be2,
                                                     hraw, agg);
    {
        pack_cat_kernel<<<120, 256, 0, stream>>>(Wm1, Wcat1p);
        int tot1 = 6 * 9 * 512;
        int tot2 = 6 * 4 * 512;
        pack_kernel<<<(tot2 + 255) / 256, 256, 0, stream>>>(Wm2, Wm2p, 128, 4, tot2);
        pack_kernel<<<(tot1 + 255) / 256, 256, 0, stream>>>(Wu1, Wu1p, 257, 9, tot1);
        pack_kernel<<<(tot2 + 255) / 256, 256, 0, stream>>>(Wu2, Wu2p, 128, 4, tot2);
    }

    for (int l = 0; l < 6; ++l) {
        premsg_kernel<<<N_NODES / 64, 512, 0, stream>>>(
            hraw, stats, (l > 0) ? 1 : 0, feat,
            Wcat1p + (size_t)l * 5 * 16 * 64 * 8, bm1 + l * 128,
            h_bf, At, As);
        message_kernel<<<N_EDGES / 64, 256, 0, stream>>>(
            At, As, src_s, tgt_s,
            Wm2p + (size_t)l * 4 * 4096, bm2 + l * 128, agg, stats);
        update_kernel<<<N_NODES / 64, 512, 0, stream>>>(
            hraw, h_bf, agg, deg, post,
            Wu1p + (size_t)l * 9 * 4096, bu1 + l * 128,
            Wu2p + (size_t)l * 4 * 4096, bu2 + l * 128, stats);
    }

    conv_kernel<<<N_NODES / 4, 256, 0, stream>>>(hraw, stats, u, Wc1, bc1, Wc2, bc2, out);
}

// Round 5
// 628.577 us; speedup vs baseline: 1.1483x; 1.0143x over previous
//
#include <hip/hip_runtime.h>
#include <stdint.h>

#define N_NODES 32768
#define N_EDGES 262144
#define NB 8
#define TW 25

typedef __attribute__((ext_vector_type(8))) short short8;
typedef __attribute__((ext_vector_type(4))) float floatx4;

#if defined(__has_builtin)
#if __has_builtin(__builtin_amdgcn_cvt_pk_bf16_f32)
#define HAVE_CVT_PK_BF16 1
#endif
#endif

// swish via HW approximate reciprocal (v_rcp_f32): ~1-ulp rel error,
// far below bf16 quantization.
__device__ __forceinline__ float swishf(float x) {
    return x * __builtin_amdgcn_rcpf(1.0f + __expf(-x));
}

__device__ __forceinline__ unsigned short f2bf(float x) {
    union { float f; unsigned u; } v; v.f = x;
    unsigned r = v.u + 0x7FFFu + ((v.u >> 16) & 1u);
    return (unsigned short)(r >> 16);
}
__device__ __forceinline__ unsigned pkbf(float a, float b) {
#ifdef HAVE_CVT_PK_BF16
    typedef __attribute__((ext_vector_type(2))) __bf16 bf16x2;
    union { bf16x2 v; unsigned u; } cv;
    cv.v = __builtin_amdgcn_cvt_pk_bf16_f32(a, b);
    return cv.u;
#else
    return (unsigned)f2bf(a) | ((unsigned)f2bf(b) << 16);
#endif
}
__device__ __forceinline__ float bf2f(unsigned short b) {
    union { unsigned u; float f; } v; v.u = ((unsigned)b) << 16; return v.f;
}
__device__ __forceinline__ float bflo(unsigned w) {
    union { unsigned u; float f; } v; v.u = w << 16; return v.f;
}
__device__ __forceinline__ float bfhi(unsigned w) {
    union { unsigned u; float f; } v; v.u = w & 0xffff0000u; return v.f;
}

// ---------------------------------------------------------------------------
__global__ void init_kernel(const float* __restrict__ pos, const float* __restrict__ u,
                            float* __restrict__ posx, float* __restrict__ post,
                            unsigned short* __restrict__ feat) {
    int i = blockIdx.x * 256 + threadIdx.x;
    if (i < N_NODES) {
        float pt = pos[i * 2 + 0] * 0.25f;
        float px = pos[i * 2 + 1] * 0.0625f;
        post[i] = pt;
        posx[i] = px;
        unsigned short f[32];
        #pragma unroll
        for (int k = 0; k < 25; ++k) f[k] = f2bf(u[(size_t)i * 25 + k]);
        f[25] = f2bf(px);
        f[26] = f2bf(pt);
        #pragma unroll
        for (int k = 27; k < 32; ++k) f[k] = 0;
        #pragma unroll
        for (int j = 0; j < 4; ++j)
            *(uint4*)(feat + (size_t)i * 32 + j * 8) = *(uint4*)&f[j * 8];
    }
}

__global__ void deg_kernel(const int* __restrict__ tgt, int* __restrict__ deg) {
    int i = blockIdx.x * 256 + threadIdx.x;
    if (i < N_EDGES) atomicAdd(&deg[tgt[i]], 1);
}

__global__ __launch_bounds__(1024) void scan_kernel(const int* __restrict__ deg,
                                                    int* __restrict__ cursor) {
    __shared__ int ps[1024];
    int t = threadIdx.x;
    int base = t * 32;
    int tot = 0;
    for (int i = 0; i < 32; ++i) tot += deg[base + i];
    ps[t] = tot;
    __syncthreads();
    for (int off = 1; off < 1024; off <<= 1) {
        int v = (t >= off) ? ps[t - off] : 0;
        __syncthreads();
        ps[t] += v;
        __syncthreads();
    }
    int run = ps[t] - tot;
    for (int i = 0; i < 32; ++i) {
        cursor[base + i] = run;
        run += deg[base + i];
    }
}

__global__ void scatter_kernel(const int* __restrict__ src, const int* __restrict__ tgt,
                               int* __restrict__ cursor,
                               int* __restrict__ src_s, int* __restrict__ tgt_s) {
    int i = blockIdx.x * 256 + threadIdx.x;
    if (i < N_EDGES) {
        int tg = tgt[i];
        int p = atomicAdd(&cursor[tg], 1);
        src_s[p] = src[i];
        tgt_s[p] = tg;
    }
}

// ---------------------------------------------------------------------------
// Generic MFMA B-frag pack: frag id = ((l*Kc + c)*8 + t8)*64 + lane.
__global__ __launch_bounds__(256) void pack_kernel(const float* __restrict__ W,
                                                   unsigned short* __restrict__ Wp,
                                                   int Kreal, int Kc, int total) {
    int id = blockIdx.x * 256 + threadIdx.x;
    if (id >= total) return;
    int lane = id & 63;
    int t8 = (id >> 6) & 7;
    int rest = id >> 9;
    int c = rest % Kc;
    int l = rest / Kc;
    int n = t8 * 16 + (lane & 15);
    int kb = c * 32 + (lane >> 4) * 8;
    short8 v;
    #pragma unroll
    for (int j = 0; j < 8; ++j) {
        int k = kb + j;
        float x = (k < Kreal) ? W[((size_t)l * Kreal + k) * 128 + n] : 0.f;
        v[j] = (short)f2bf(x);
    }
    *(short8*)(Wp + (size_t)id * 8) = v;
}

// Combined pre-projection weight Wcat (160 x 384), tiles 0..7 = A_t (from Wm1),
// 8..15 = A_s (Wm1, h-shifted / diff-negated), 16..23 = Uh (Wu1 h-part).
// frag id = ((l*5 + c)*24 + tile)*64 + lane; total 6*5*24*64 = 46080.
__global__ __launch_bounds__(256) void pack_cat_kernel(const float* __restrict__ Wm1,
                                                       const float* __restrict__ Wu1,
                                                       unsigned short* __restrict__ Wp) {
    int id = blockIdx.x * 256 + threadIdx.x;
    if (id >= 46080) return;
    int lane = id & 63;
    int tmp = id >> 6;
    int tile = tmp % 24;
    int tmp2 = tmp / 24;
    int c = tmp2 % 5;
    int l = tmp2 / 5;
    int n = tile * 16 + (lane & 15);      // 0..383
    int grp = n >> 7;                     // 0=T, 1=S, 2=U
    int col = n & 127;
    int kb = c * 32 + (lane >> 4) * 8;
    const float* Wm = Wm1 + (size_t)l * 283 * 128;
    const float* Wu = Wu1 + (size_t)l * 257 * 128;
    short8 v;
    #pragma unroll
    for (int j = 0; j < 8; ++j) {
        int k = kb + j;
        float x = 0.f;
        if (grp == 2) {
            if (k < 128) x = Wu[(size_t)k * 128 + col];
        } else if (k < 128) {
            x = Wm[(size_t)(grp ? 128 + k : k) * 128 + col];
        } else if (k < 155) {
            int row = 256 + (k - 128);    // 256..282
            x = Wm[(size_t)row * 128 + col];
            if (grp) x = (row == 282) ? 0.f : -x;
        }
        v[j] = (short)f2bf(x);
    }
    *(short8*)(Wp + (size_t)id * 8) = v;
}

// Update GEMM1 agg-part weight: K=160 ([agg(128) | post(1) | pad]), cols 128.
// k<128 -> Wu1 row 128+k; k==128 -> row 256; else 0.
// frag id = ((l*5 + c)*8 + t8)*64 + lane; total 6*5*8*64 = 15360.
__global__ __launch_bounds__(256) void pack_upd_kernel(const float* __restrict__ Wu1,
                                                       unsigned short* __restrict__ Wp) {
    int id = blockIdx.x * 256 + threadIdx.x;
    if (id >= 15360) return;
    int lane = id & 63;
    int t8 = (id >> 6) & 7;
    int rest = id >> 9;
    int c = rest % 5;
    int l = rest / 5;
    int n = t8 * 16 + (lane & 15);
    int kb = c * 32 + (lane >> 4) * 8;
    const float* Wu = Wu1 + (size_t)l * 257 * 128;
    short8 v;
    #pragma unroll
    for (int j = 0; j < 8; ++j) {
        int k = kb + j;
        float x = 0.f;
        if (k < 128) x = Wu[(size_t)(128 + k) * 128 + n];
        else if (k == 128) x = Wu[(size_t)256 * 128 + n];
        v[j] = (short)f2bf(x);
    }
    *(short8*)(Wp + (size_t)id * 8) = v;
}

// ---------------------------------------------------------------------------
// Encoder; writes hraw (bf16, unnormalized h) and zeroes this block's agg slice
__global__ __launch_bounds__(256) void encoder_kernel(
    const float* __restrict__ u, const float* __restrict__ posx,
    const float* __restrict__ post,
    const float* __restrict__ We1, const float* __restrict__ be1,
    const float* __restrict__ We2, const float* __restrict__ be2,
    unsigned short* __restrict__ hraw, float* __restrict__ agg)
{
    __shared__ __align__(16) float As_[64 * 36];
    __shared__ __align__(16) float Ws[32 * 128];
    __shared__ __align__(16) float Ms[64 * 128];

    int t = threadIdx.x;
    int n0 = blockIdx.x * 64;
    int rg = t >> 5, cg = t & 31;

    {   // zero agg slice
        int r = t & 63, cseg = t >> 6;
        float4 z = make_float4(0.f, 0.f, 0.f, 0.f);
        #pragma unroll
        for (int j = 0; j < 8; ++j)
            *(float4*)(agg + (size_t)(n0 + r) * 128 + cseg * 32 + j * 4) = z;
    }

    float acc[8][4] = {};
    {
        int kk = t >> 3, cb = (t & 7) * 16;
        #pragma unroll
        for (int j = 0; j < 4; ++j) {
            float4 w = make_float4(0.f, 0.f, 0.f, 0.f);
            if (kk < 27) w = *(const float4*)&We1[kk * 128 + cb + j * 4];
            *(float4*)&Ws[kk * 128 + cb + j * 4] = w;
        }
        int el = t >> 2, kb = (t & 3) * 8, n = n0 + el;
        float v[8];
        #pragma unroll
        for (int j = 0; j < 8; ++j) {
            int k = kb + j;
            float x = 0.f;
            if (k < 25) x = u[n * 25 + k];
            else if (k == 25) x = posx[n];
            else if (k == 26) x = post[n];
            v[j] = x;
        }
        #pragma unroll
        for (int j = 0; j < 8; j += 4)
            *(float4*)&As_[el * 36 + kb + j] = make_float4(v[j], v[j+1], v[j+2], v[j+3]);
        __syncthreads();
        #pragma unroll 4
        for (int kk2 = 0; kk2 < 32; ++kk2) {
            float4 b = *(const float4*)&Ws[kk2 * 128 + cg * 4];
            float a[8];
            #pragma unroll
            for (int i = 0; i < 8; ++i) a[i] = As_[(rg * 8 + i) * 36 + kk2];
            #pragma unroll
            for (int i = 0; i < 8; ++i) {
                acc[i][0] += a[i] * b.x; acc[i][1] += a[i] * b.y;
                acc[i][2] += a[i] * b.z; acc[i][3] += a[i] * b.w;
            }
        }
        __syncthreads();
    }
    {
        float4 b1 = *(const float4*)&be1[cg * 4];
        #pragma unroll
        for (int i = 0; i < 8; ++i) {
            float4 m;
            m.x = swishf(acc[i][0] + b1.x);
            m.y = swishf(acc[i][1] + b1.y);
            m.z = swishf(acc[i][2] + b1.z);
            m.w = swishf(acc[i][3] + b1.w);
            *(float4*)&Ms[(rg * 8 + i) * 128 + cg * 4] = m;
        }
        __syncthreads();
    }
    float acc2[8][4] = {};
    for (int k0 = 0; k0 < 128; k0 += 32) {
        int kk = t >> 3, cb = (t & 7) * 16;
        #pragma unroll
        for (int j = 0; j < 4; ++j)
            *(float4*)&Ws[kk * 128 + cb + j * 4] =
                *(const float4*)&We2[(k0 + kk) * 128 + cb + j * 4];
        __syncthreads();
        #pragma unroll 4
        for (int kk2 = 0; kk2 < 32; ++kk2) {
            float4 b = *(const float4*)&Ws[kk2 * 128 + cg * 4];
            float a[8];
            #pragma unroll
            for (int i = 0; i < 8; ++i) a[i] = Ms[(rg * 8 + i) * 128 + (k0 + kk2)];
            #pragma unroll
            for (int i = 0; i < 8; ++i) {
                acc2[i][0] += a[i] * b.x; acc2[i][1] += a[i] * b.y;
                acc2[i][2] += a[i] * b.z; acc2[i][3] += a[i] * b.w;
            }
        }
        __syncthreads();
    }
    {
        float4 b2 = *(const float4*)&be2[cg * 4];
        #pragma unroll
        for (int i = 0; i < 8; ++i) {
            int n = n0 + rg * 8 + i;
            float4 o;
            o.x = swishf(acc2[i][0] + b2.x);
            o.y = swishf(acc2[i][1] + b2.y);
            o.z = swishf(acc2[i][2] + b2.z);
            o.w = swishf(acc2[i][3] + b2.w);
            uint2 pk;
            pk.x = pkbf(o.x, o.y);
            pk.y = pkbf(o.z, o.w);
            *(uint2*)(hraw + (size_t)n * 128 + cg * 4) = pk;
        }
    }
}

// ---------------------------------------------------------------------------
// Per-node pre-projection:
//   h_norm -> h_bf;  [A_t | A_s | Uh] = [h_norm(128)|feat(32)] @ Wcat(160x384)
//   (+bm1 on A_t, +bu1 on Uh). All three outputs bf16.
// 64 nodes/block, 512 threads; wave w owns col tiles w, 8+w, 16+w.
__global__ __launch_bounds__(512, 4) void premsg_kernel(
    const unsigned short* __restrict__ hraw,
    const float* __restrict__ stats, int donorm,
    const unsigned short* __restrict__ feat,
    const unsigned short* __restrict__ Wp,
    const float* __restrict__ b1, const float* __restrict__ bu1,
    unsigned short* __restrict__ h_bf,
    unsigned short* __restrict__ At, unsigned short* __restrict__ As,
    unsigned short* __restrict__ Uh)
{
    __shared__ __align__(16) unsigned short A[64 * 168];   // 21504 B
    __shared__ float mean_s[128];
    __shared__ float rstd_s[128];

    int t = threadIdx.x;
    int n0 = blockIdx.x * 64;
    int bidx = n0 >> 12;

    if (t < 128) {
        float mn = 0.f, rs = 1.f;
        if (donorm) {
            float s1 = stats[bidx * 128 + t] * (1.f / 4096.f);
            float s2 = stats[(NB + bidx) * 128 + t] * (1.f / 4096.f);
            mn = s1;
            rs = rsqrtf(s2 - s1 * s1 + 1e-5f);
        }
        mean_s[t] = mn;
        rstd_s[t] = rs;
    }
    __syncthreads();

    {   // stage [h_norm | feat] into LDS; also write h_bf
        int r = t & 63, cseg = t >> 6;
        int n = n0 + r;
        uint4 raw0 = *(const uint4*)(hraw + (size_t)n * 128 + cseg * 16);
        uint4 raw1 = *(const uint4*)(hraw + (size_t)n * 128 + cseg * 16 + 8);
        unsigned pk[8];
        #pragma unroll
        for (int j = 0; j < 8; ++j) {
            unsigned word = (j < 4) ? ((const unsigned*)&raw0)[j]
                                    : ((const unsigned*)&raw1)[j - 4];
            int c0 = cseg * 16 + j * 2;
            float v0 = (bf2f((unsigned short)(word & 0xffffu)) - mean_s[c0]) * rstd_s[c0];
            float v1 = (bf2f((unsigned short)(word >> 16)) - mean_s[c0 + 1]) * rstd_s[c0 + 1];
            pk[j] = pkbf(v0, v1);
        }
        *(uint4*)(A + r * 168 + cseg * 16)     = *(uint4*)&pk[0];
        *(uint4*)(A + r * 168 + cseg * 16 + 8) = *(uint4*)&pk[4];
        *(uint4*)(h_bf + (size_t)n * 128 + cseg * 16)     = *(uint4*)&pk[0];
        *(uint4*)(h_bf + (size_t)n * 128 + cseg * 16 + 8) = *(uint4*)&pk[4];
        if (cseg < 2) {
            uint4 f0 = *(const uint4*)(feat + (size_t)n * 32 + cseg * 16);
            uint4 f1 = *(const uint4*)(feat + (size_t)n * 32 + cseg * 16 + 8);
            *(uint4*)(A + r * 168 + 128 + cseg * 16)     = f0;
            *(uint4*)(A + r * 168 + 128 + cseg * 16 + 8) = f1;
        }
    }
    __syncthreads();

    int w = t >> 6, lane = t & 63, q = lane >> 4, m = lane & 15;
    floatx4 accT[4] = {};
    floatx4 accS[4] = {};
    floatx4 accU[4] = {};
    #pragma unroll
    for (int c = 0; c < 5; ++c) {
        short8 bT = *(const short8*)(Wp + ((size_t)(c * 24 + w) * 64 + lane) * 8);
        short8 bS = *(const short8*)(Wp + ((size_t)(c * 24 + 8 + w) * 64 + lane) * 8);
        short8 bU = *(const short8*)(Wp + ((size_t)(c * 24 + 16 + w) * 64 + lane) * 8);
        #pragma unroll
        for (int g2 = 0; g2 < 4; ++g2) {
            short8 a = *(const short8*)(A + (g2 * 16 + m) * 168 + c * 32 + q * 8);
            accT[g2] = __builtin_amdgcn_mfma_f32_16x16x32_bf16(a, bT, accT[g2], 0, 0, 0);
            accS[g2] = __builtin_amdgcn_mfma_f32_16x16x32_bf16(a, bS, accS[g2], 0, 0, 0);
            accU[g2] = __builtin_amdgcn_mfma_f32_16x16x32_bf16(a, bU, accU[g2], 0, 0, 0);
        }
    }
    int col = w * 16 + m;
    float bvT = b1[col];
    float bvU = bu1[col];
    #pragma unroll
    for (int g2 = 0; g2 < 4; ++g2) {
        #pragma unroll
        for (int r = 0; r < 4; ++r) {
            int row = g2 * 16 + q * 4 + r;
            size_t idx = (size_t)(n0 + row) * 128 + col;
            At[idx] = f2bf(accT[g2][r] + bvT);
            As[idx] = f2bf(accS[g2][r]);
            Uh[idx] = f2bf(accU[g2][r] + bvU);
        }
    }
}

// ---------------------------------------------------------------------------
// Message: register-A, bf16 gathers, barrier-free, forced-MLP gathers.
// 64 tgt-sorted edges/block, 256 threads (4 waves); wave w owns edges
// w*16..w*16+16 x ALL 128 output cols.
__global__ __launch_bounds__(256, 6) void message_kernel(
    const unsigned short* __restrict__ At, const unsigned short* __restrict__ As,
    const int* __restrict__ src_s, const int* __restrict__ tgt_s,
    const unsigned short* __restrict__ W2p, const float* __restrict__ b2,
    float* __restrict__ agg, float* __restrict__ stats)
{
    __shared__ __align__(16) unsigned short Cs[64 * 132];   // 16896 B
    __shared__ int tgtS[64];

    int t = threadIdx.x;
    int e0 = blockIdx.x * 64;
    if (blockIdx.x == 0) {  // zero stats for this layer
        float4 z = make_float4(0.f, 0.f, 0.f, 0.f);
        *(float4*)&stats[t * 8] = z;
        *(float4*)&stats[t * 8 + 4] = z;
    }

    int w = t >> 6, lane = t & 63, q = lane >> 4, m = lane & 15;
    int erow = w * 16 + m;
    int e = e0 + erow;
    int gg = tgt_s[e];               // global read (no barrier dependency)
    int ss = src_s[e];
    if (lane < 16) tgtS[w * 16 + lane] = tgt_s[e0 + w * 16 + lane];  // wave-private

    // ---- gather At/As bf16 k-slices; force all 8 loads issued before any use
    const unsigned short* atp = At + (size_t)gg * 128 + q * 8;
    const unsigned short* asp = As + (size_t)ss * 128 + q * 8;
    uint4 wa[4], wb[4];
    #pragma unroll
    for (int c = 0; c < 4; ++c) {
        wa[c] = *(const uint4*)(atp + c * 32);
        wb[c] = *(const uint4*)(asp + c * 32);
    }
    __builtin_amdgcn_sched_barrier(0);   // keep all 8 gathers in flight

    // ---- A-frags in registers: unpack + add + swish + repack
    short8 af[4];
    #pragma unroll
    for (int c = 0; c < 4; ++c) {
        const unsigned* ua = (const unsigned*)&wa[c];
        const unsigned* ub = (const unsigned*)&wb[c];
        union { unsigned u[4]; short8 s; } pk_;
        #pragma unroll
        for (int j = 0; j < 4; ++j) {
            float lo = swishf(bflo(ua[j]) + bflo(ub[j]));
            float hi = swishf(bfhi(ua[j]) + bfhi(ub[j]));
            pk_.u[j] = pkbf(lo, hi);
        }
        af[c] = pk_.s;
    }

    // ---- GEMM2: 4 K-chunks x 8 col-tiles
    floatx4 acc[8] = {};
    #pragma unroll
    for (int c = 0; c < 4; ++c) {
        #pragma unroll
        for (int t8 = 0; t8 < 8; ++t8) {
            short8 b = *(const short8*)(W2p + ((size_t)(c * 8 + t8) * 64 + lane) * 8);
            acc[t8] = __builtin_amdgcn_mfma_f32_16x16x32_bf16(af[c], b, acc[t8], 0, 0, 0);
        }
    }

    // ---- epilogue: swish + write per-wave Cs region
    #pragma unroll
    for (int t8 = 0; t8 < 8; ++t8) {
        float bv = b2[t8 * 16 + m];
        unsigned p01 = pkbf(swishf(acc[t8][0] + bv), swishf(acc[t8][1] + bv));
        unsigned p23 = pkbf(swishf(acc[t8][2] + bv), swishf(acc[t8][3] + bv));
        int rb = (w * 16 + q * 4) * 132 + t8 * 16 + m;
        Cs[rb]           = (unsigned short)p01;
        Cs[rb + 132]     = (unsigned short)(p01 >> 16);
        Cs[rb + 2 * 132] = (unsigned short)p23;
        Cs[rb + 3 * 132] = (unsigned short)(p23 >> 16);
    }

    // ---- reduction over this wave's 16 rows (wave-synchronous LDS)
    {
        int r0 = w * 16;
        int col0 = lane;
        float run0 = 0.f, run1 = 0.f;
        int prev = tgtS[r0];
        bool atStart = true;
        #pragma unroll 4
        for (int i = 0; i < 16; ++i) {
            int tg = tgtS[r0 + i];
            if (tg != prev) {
                float* d0 = &agg[(size_t)prev * 128 + col0];
                if (atStart) { atomicAdd(d0, run0); atomicAdd(d0 + 64, run1); }
                else         { d0[0] = run0;        d0[64] = run1; }
                run0 = 0.f; run1 = 0.f; prev = tg; atStart = false;
            }
            run0 += bf2f(Cs[(r0 + i) * 132 + col0]);
            run1 += bf2f(Cs[(r0 + i) * 132 + col0 + 64]);
        }
        float* d0 = &agg[(size_t)prev * 128 + col0];
        atomicAdd(d0, run0);
        atomicAdd(d0 + 64, run1);
    }
}

// ---------------------------------------------------------------------------
// Update MLP, slimmed: GEMM1 K=160 ([agg/deg | post | pad]); h-part comes in
// as Uh (premsg). LDS 38.9 KB -> 4 blocks/CU. Residual read from h_bf global.
__global__ __launch_bounds__(512, 8) void update_kernel(
    unsigned short* __restrict__ hraw, const unsigned short* __restrict__ h_bf,
    const unsigned short* __restrict__ Uh,
    float* __restrict__ agg, const int* __restrict__ deg,
    const float* __restrict__ post,
    const unsigned short* __restrict__ W1p,
    const unsigned short* __restrict__ W2p, const float* __restrict__ b2,
    float* __restrict__ stats)
{
    __shared__ __align__(16) unsigned short A[64 * 168];    // 21504 B
    __shared__ __align__(16) unsigned short Msh[64 * 136];  // 17408 B

    int t = threadIdx.x;
    int n0 = blockIdx.x * 64;

    // ---- stage A = [agg/deg (bf16, 128) | post (1) | zeros]: 8 threads/row
    {
        int r = t & 63, cseg = t >> 6;
        int n = n0 + r;
        float ic = __builtin_amdgcn_rcpf(fmaxf((float)deg[n], 1.0f));
        const float* ap = agg + (size_t)n * 128 + cseg * 16;
        float4 v0 = *(const float4*)ap;
        float4 v1 = *(const float4*)(ap + 4);
        float4 v2 = *(const float4*)(ap + 8);
        float4 v3 = *(const float4*)(ap + 12);
        unsigned pa[8];
        pa[0] = pkbf(v0.x * ic, v0.y * ic);
        pa[1] = pkbf(v0.z * ic, v0.w * ic);
        pa[2] = pkbf(v1.x * ic, v1.y * ic);
        pa[3] = pkbf(v1.z * ic, v1.w * ic);
        pa[4] = pkbf(v2.x * ic, v2.y * ic);
        pa[5] = pkbf(v2.z * ic, v2.w * ic);
        pa[6] = pkbf(v3.x * ic, v3.y * ic);
        pa[7] = pkbf(v3.z * ic, v3.w * ic);
        *(uint4*)(A + r * 168 + cseg * 16)     = *(uint4*)&pa[0];
        *(uint4*)(A + r * 168 + cseg * 16 + 8) = *(uint4*)&pa[4];
        if (cseg < 4) {   // cols 128..159: post at 128, zeros elsewhere
            short8 z;
            #pragma unroll
            for (int k = 0; k < 8; ++k) z[k] = 0;
            if (cseg == 0) z[0] = (short)f2bf(post[n]);
            *(short8*)(A + r * 168 + 128 + cseg * 8) = z;
        }
    }
    __syncthreads();

    int w = t >> 6, lane = t & 63, q = lane >> 4, m = lane & 15;
    int col = w * 16 + m;

    floatx4 acc[4] = {};
    #pragma unroll
    for (int c = 0; c < 5; ++c) {
        short8 b = *(const short8*)(W1p + ((size_t)(c * 8 + w) * 64 + lane) * 8);
        #pragma unroll
        for (int g2 = 0; g2 < 4; ++g2) {
            short8 a = *(const short8*)(A + (g2 * 16 + m) * 168 + c * 32 + q * 8);
            acc[g2] = __builtin_amdgcn_mfma_f32_16x16x32_bf16(a, b, acc[g2], 0, 0, 0);
        }
    }
    // ---- epilogue1: + Uh (bias folded), swish -> Msh
    {
        #pragma unroll
        for (int g2 = 0; g2 < 4; ++g2) {
            int rowb = g2 * 16 + q * 4;
            float v0 = swishf(acc[g2][0] + bf2f(Uh[(size_t)(n0 + rowb + 0) * 128 + col]));
            float v1 = swishf(acc[g2][1] + bf2f(Uh[(size_t)(n0 + rowb + 1) * 128 + col]));
            float v2 = swishf(acc[g2][2] + bf2f(Uh[(size_t)(n0 + rowb + 2) * 128 + col]));
            float v3 = swishf(acc[g2][3] + bf2f(Uh[(size_t)(n0 + rowb + 3) * 128 + col]));
            unsigned p01 = pkbf(v0, v1);
            unsigned p23 = pkbf(v2, v3);
            Msh[(rowb + 0) * 136 + col] = (unsigned short)p01;
            Msh[(rowb + 1) * 136 + col] = (unsigned short)(p01 >> 16);
            Msh[(rowb + 2) * 136 + col] = (unsigned short)p23;
            Msh[(rowb + 3) * 136 + col] = (unsigned short)(p23 >> 16);
        }
    }
    __syncthreads();

    floatx4 acc2[4] = {};
    #pragma unroll
    for (int c = 0; c < 4; ++c) {
        short8 b = *(const short8*)(W2p + ((size_t)(c * 8 + w) * 64 + lane) * 8);
        #pragma unroll
        for (int g2 = 0; g2 < 4; ++g2) {
            short8 a = *(const short8*)(Msh + (g2 * 16 + m) * 136 + c * 32 + q * 8);
            acc2[g2] = __builtin_amdgcn_mfma_f32_16x16x32_bf16(a, b, acc2[g2], 0, 0, 0);
        }
    }

    // ---- epilogue2: residual from h_bf, fused stats, hraw write, zero agg
    int bidx = n0 >> 12;
    float bv = b2[col];
    float s = 0.f, s2 = 0.f;
    #pragma unroll
    for (int g2 = 0; g2 < 4; ++g2) {
        #pragma unroll
        for (int r = 0; r < 4; ++r) {
            int row = g2 * 16 + q * 4 + r;
            float res = bf2f(h_bf[(size_t)(n0 + row) * 128 + col]);
            float hv = res + swishf(acc2[g2][r] + bv);
            hraw[(size_t)(n0 + row) * 128 + col] = f2bf(hv);
            s += hv; s2 += hv * hv;
        }
    }
    s  += __shfl_xor(s, 16);  s  += __shfl_xor(s, 32);
    s2 += __shfl_xor(s2, 16); s2 += __shfl_xor(s2, 32);
    if (q == 0) {
        atomicAdd(&stats[bidx * 128 + col], s);
        atomicAdd(&stats[(NB + bidx) * 128 + col], s2);
    }
    {   // zero agg slice for next layer
        int r = t & 63, cseg = t >> 6;
        float4 z = make_float4(0.f, 0.f, 0.f, 0.f);
        #pragma unroll
        for (int j = 0; j < 4; ++j)
            *(float4*)(agg + (size_t)(n0 + r) * 128 + cseg * 16 + j * 4) = z;
    }
}

// ---------------------------------------------------------------------------
// Conv head: 4 nodes/block, one wave per node; final-layer norm folded here.
__global__ __launch_bounds__(256) void conv_kernel(
    const unsigned short* __restrict__ hraw, const float* __restrict__ stats,
    const float* __restrict__ u,
    const float* __restrict__ Wc1, const float* __restrict__ bc1,
    const float* __restrict__ Wc2, const float* __restrict__ bc2,
    float* __restrict__ out)
{
    __shared__ float hs[4][128];
    __shared__ float c1[4][8 * 40];
    int w = threadIdx.x >> 6, lane = threadIdx.x & 63;
    int n = blockIdx.x * 4 + w;
    int b = n >> 12;
    #pragma unroll
    for (int h2 = 0; h2 < 2; ++h2) {
        int c = lane + h2 * 64;
        float s1 = stats[b * 128 + c] * (1.f / 4096.f);
        float s2 = stats[(NB + b) * 128 + c] * (1.f / 4096.f);
        float rs = rsqrtf(s2 - s1 * s1 + 1e-5f);
        hs[w][c] = (bf2f(hraw[(size_t)n * 128 + c]) - s1) * rs;
    }
    __syncthreads();
    for (int idx = lane; idx < 304; idx += 64) {
        int o = idx / 38, p = idx % 38;
        float s = bc1[o];
        #pragma unroll
        for (int k = 0; k < 16; ++k) s += hs[w][p * 3 + k] * Wc1[o * 16 + k];
        c1[w][o * 40 + p] = swishf(s);
    }
    __syncthreads();
    if (lane < TW) {
        float s = bc2[0];
        #pragma unroll
        for (int o = 0; o < 8; ++o)
            for (int k = 0; k < 14; ++k)
                s += c1[w][o * 40 + lane + k] * Wc2[o * 14 + k];
        float dt_cum = (float)(lane + 1) * (4.0f / 250.0f);
        out[n * TW + lane] = u[n * 25 + 24] + dt_cum * s;
    }
}

// ---------------------------------------------------------------------------
extern "C" void kernel_launch(void* const* d_in, const int* in_sizes, int n_in,
                              void* d_out, int out_size, void* d_ws, size_t ws_size,
                              hipStream_t stream)
{
    const float* u   = (const float*)d_in[0];
    const float* pos = (const float*)d_in[1];
    const int*   ei  = (const int*)d_in[2];
    const float* We1 = (const float*)d_in[4];
    const float* be1 = (const float*)d_in[5];
    const float* We2 = (const float*)d_in[6];
    const float* be2 = (const float*)d_in[7];
    const float* Wm1 = (const float*)d_in[8];
    const float* bm1 = (const float*)d_in[9];
    const float* Wm2 = (const float*)d_in[10];
    const float* bm2 = (const float*)d_in[11];
    const float* Wu1 = (const float*)d_in[12];
    const float* bu1 = (const float*)d_in[13];
    const float* Wu2 = (const float*)d_in[14];
    const float* bu2 = (const float*)d_in[15];
    const float* Wc1 = (const float*)d_in[16];
    const float* bc1 = (const float*)d_in[17];
    const float* Wc2 = (const float*)d_in[18];
    const float* bc2 = (const float*)d_in[19];
    float* out = (float*)d_out;

    char* base = (char*)d_ws;
    size_t off = 0;
    auto alloc = [&](size_t bytes) -> char* {
        char* r = base + off;
        off = (off + bytes + 511) & ~(size_t)511;
        return r;
    };
    unsigned short* hraw   = (unsigned short*)alloc((size_t)N_NODES * 128 * 2);
    unsigned short* h_bf   = (unsigned short*)alloc((size_t)N_NODES * 128 * 2);
    float*          agg    = (float*)alloc((size_t)N_NODES * 128 * 4);
    unsigned short* At     = (unsigned short*)alloc((size_t)N_NODES * 128 * 2);
    unsigned short* As     = (unsigned short*)alloc((size_t)N_NODES * 128 * 2);
    unsigned short* Uh     = (unsigned short*)alloc((size_t)N_NODES * 128 * 2);
    float*          posx   = (float*)alloc(N_NODES * 4);
    float*          post   = (float*)alloc(N_NODES * 4);
    unsigned short* feat   = (unsigned short*)alloc((size_t)N_NODES * 32 * 2);
    float*          stats  = (float*)alloc(2 * NB * 128 * 4);
    int*            deg    = (int*)alloc(N_NODES * 4);
    int*            cursor = (int*)alloc(N_NODES * 4);
    int*            src_s  = (int*)alloc((size_t)N_EDGES * 4);
    int*            tgt_s  = (int*)alloc((size_t)N_EDGES * 4);
    unsigned short* Wcat1p = (unsigned short*)alloc((size_t)46080 * 8 * 2);
    unsigned short* Wm2p   = (unsigned short*)alloc((size_t)6 * 4 * 4096 * 2);
    unsigned short* Wu1p   = (unsigned short*)alloc((size_t)15360 * 8 * 2);
    unsigned short* Wu2p   = (unsigned short*)alloc((size_t)6 * 4 * 4096 * 2);
    (void)ws_size;

    const int* srcp = ei;
    const int* tgtp = ei + N_EDGES;

    init_kernel<<<N_NODES / 256, 256, 0, stream>>>(pos, u, posx, post, feat);
    hipMemsetAsync(deg, 0, N_NODES * sizeof(int), stream);
    deg_kernel<<<N_EDGES / 256, 256, 0, stream>>>(tgtp, deg);
    scan_kernel<<<1, 1024, 0, stream>>>(deg, cursor);
    scatter_kernel<<<N_EDGES / 256, 256, 0, stream>>>(srcp, tgtp, cursor, src_s, tgt_s);
    encoder_kernel<<<N_NODES / 64, 256, 0, stream>>>(u, posx, post, We1, be1, We2, be2,
                                                     hraw, agg);
    {
        pack_cat_kernel<<<180, 256, 0, stream>>>(Wm1, Wu1, Wcat1p);
        pack_upd_kernel<<<60, 256, 0, stream>>>(Wu1, Wu1p);
        int tot2 = 6 * 4 * 512;
        pack_kernel<<<(tot2 + 255) / 256, 256, 0, stream>>>(Wm2, Wm2p, 128, 4, tot2);
        pack_kernel<<<(tot2 + 255) / 256, 256, 0, stream>>>(Wu2, Wu2p, 128, 4, tot2);
    }

    for (int l = 0; l < 6; ++l) {
        premsg_kernel<<<N_NODES / 64, 512, 0, stream>>>(
            hraw, stats, (l > 0) ? 1 : 0, feat,
            Wcat1p + (size_t)l * 5 * 24 * 512, bm1 + l * 128, bu1 + l * 128,
            h_bf, At, As, Uh);
        message_kernel<<<N_EDGES / 64, 256, 0, stream>>>(
            At, As, src_s, tgt_s,
            Wm2p + (size_t)l * 4 * 4096, bm2 + l * 128, agg, stats);
        update_kernel<<<N_NODES / 64, 512, 0, stream>>>(
            hraw, h_bf, Uh, agg, deg, post,
            Wu1p + (size_t)l * 5 * 8 * 512,
            Wu2p + (size_t)l * 4 * 4096, bu2 + l * 128, stats);
    }

    conv_kernel<<<N_NODES / 4, 256, 0, stream>>>(hraw, stats, u, Wc1, bc1, Wc2, bc2, out);
}